// Round 7
// baseline (96.957 us; speedup 1.0000x reference)
//
#include <hip/hip_runtime.h>
#include <hip/hip_bf16.h>
#include <math.h>

#define BB 8
#define LL 1024
#define DD 512
#define VV 64
#define KK 8

constexpr float INV_TEMP = 10.0f;   // 1/TEMP
constexpr float EPSF     = 1e-10f;

// ---------------- workspace float layout (NO atomics, NO memset) ------------
// every slot is written unconditionally by its producer block
#define WS_DENP   0                       // den partials [8192][8]
#define WS_CLS    (8192*8)                // cls  per-block {sum,cnt} x 2048
#define WS_EMP    (WS_CLS + 4096)         // emp  per-block {sum,cnt} x 2048
#define WS_CONTR  (WS_EMP + 4096)         // contr per-block {sum,cnt} x 4096
#define WS_PTRROW (WS_CONTR + 8192)       // ptr per-row {sumd,cnt} x 8192

typedef __attribute__((ext_vector_type(8))) short  short8;
typedef __attribute__((ext_vector_type(4))) float  f32x4;

// ---------------- bool-dtype detection ----------------
// MUST be fed attention_mask: its first L entries are all-True by construction.
__device__ __forceinline__ int mask_mode(const void* att_raw) {
    const unsigned* w = (const unsigned*)att_raw;
    unsigned w0 = w[0];
    if (w0 == 0x01010101u) return 0;           // bool/uint8
    if (w0 == 0x3f800000u) return 2;           // float32
    if (w0 == 1u) return (w[1] == 0u) ? 3 : 1; // int64 : int32
    return 0;
}
__device__ __forceinline__ bool get_mask(const void* p, int idx, int mode) {
    if (mode == 0) return ((const unsigned char*)p)[idx] != 0;
    if (mode == 1) return ((const int*)p)[idx] != 0;
    if (mode == 3) return ((const unsigned*)p)[2*idx] != 0u;
    return ((const float*)p)[idx] != 0.0f;
}

__device__ __forceinline__ float wave_red_sum(float v) {
    #pragma unroll
    for (int off = 32; off; off >>= 1) v += __shfl_xor(v, off);
    return v;
}
__device__ __forceinline__ float wave_red_max(float v) {
    #pragma unroll
    for (int off = 32; off; off >>= 1) v = fmaxf(v, __shfl_xor(v, off));
    return v;
}

__device__ __forceinline__ short bfb(float f) {
    __hip_bfloat16 h = __float2bfloat16(f);
    union { __hip_bfloat16 h; short u; } c; c.h = h; return c.u;
}

#define BM 128
#define BKD 32
#define ST 40            // LDS row stride in shorts (80 bytes)

// ================= mega kernel: all independent work in one launch ==========
// grid = 512 groups x 21 blocks: [den x1, cls x4, contr x8, empty x4, ptr x4]
__global__ __launch_bounds__(256) void k_mega(
        const float* __restrict__ box,     const float* __restrict__ tag,
        const float* __restrict__ logits,  const int* __restrict__ tok,
        const int* __restrict__ bidx,      const float* __restrict__ emptyp,
        const float* __restrict__ row_sim, const float* __restrict__ col_sim,
        const float* __restrict__ row_coef,const float* __restrict__ col_coef,
        const void* __restrict__ dtm_raw,  const void* __restrict__ att_raw,
        float* __restrict__ ws) {
    __shared__ short As[BM * ST];
    __shared__ short Bs[BM * ST];

    int bid = blockIdx.x;
    int g   = bid / 21;
    int r   = bid - g * 21;
    int tid  = threadIdx.x;
    int lane = tid & 63;
    int wv   = tid >> 6;

    if (r == 0) {
        // ---------------- den: bf16 MFMA GEMM + masked exp row-sum ----------
        int b     = g & 7;
        int tile  = g >> 3;             // 0..63
        int l0    = (tile >> 3) * BM;
        int ttile = tile & 7;
        int t0    = ttile * BM;
        int wr = wv >> 1, wc = wv & 1;

        int srow  = tid >> 1;
        int shalf = tid & 1;
        const float* gA = box + ((size_t)b * LL + l0 + srow) * DD + shalf * 16;
        const float* gB = tag + ((size_t)b * LL + t0 + srow) * DD + shalf * 16;
        short* wA = &As[srow * ST + shalf * 16];
        short* wB = &Bs[srow * ST + shalf * 16];

        f32x4 acc[4][4];
        #pragma unroll
        for (int m = 0; m < 4; m++)
            #pragma unroll
            for (int n = 0; n < 4; n++) acc[m][n] = (f32x4){0.f, 0.f, 0.f, 0.f};

        int k0 = (lane >> 4) * 8;
        const short* rA = &As[(wr * 64 + (lane & 15)) * ST + k0];
        const short* rB = &Bs[(wc * 64 + (lane & 15)) * ST + k0];

        for (int d0 = 0; d0 < DD; d0 += BKD) {
            __syncthreads();
            float4 fa0 = *(const float4*)(gA + d0);
            float4 fa1 = *(const float4*)(gA + d0 + 4);
            float4 fa2 = *(const float4*)(gA + d0 + 8);
            float4 fa3 = *(const float4*)(gA + d0 + 12);
            float4 fb0 = *(const float4*)(gB + d0);
            float4 fb1 = *(const float4*)(gB + d0 + 4);
            float4 fb2 = *(const float4*)(gB + d0 + 8);
            float4 fb3 = *(const float4*)(gB + d0 + 12);
            short8 va0 = {bfb(fa0.x), bfb(fa0.y), bfb(fa0.z), bfb(fa0.w),
                          bfb(fa1.x), bfb(fa1.y), bfb(fa1.z), bfb(fa1.w)};
            short8 va1 = {bfb(fa2.x), bfb(fa2.y), bfb(fa2.z), bfb(fa2.w),
                          bfb(fa3.x), bfb(fa3.y), bfb(fa3.z), bfb(fa3.w)};
            short8 vb0 = {bfb(fb0.x), bfb(fb0.y), bfb(fb0.z), bfb(fb0.w),
                          bfb(fb1.x), bfb(fb1.y), bfb(fb1.z), bfb(fb1.w)};
            short8 vb1 = {bfb(fb2.x), bfb(fb2.y), bfb(fb2.z), bfb(fb2.w),
                          bfb(fb3.x), bfb(fb3.y), bfb(fb3.z), bfb(fb3.w)};
            *(short8*)wA       = va0;
            *(short8*)(wA + 8) = va1;
            *(short8*)wB       = vb0;
            *(short8*)(wB + 8) = vb1;
            __syncthreads();

            short8 af[4], bf[4];
            #pragma unroll
            for (int m = 0; m < 4; m++) af[m] = *(const short8*)(rA + m * 16 * ST);
            #pragma unroll
            for (int n = 0; n < 4; n++) bf[n] = *(const short8*)(rB + n * 16 * ST);
            #pragma unroll
            for (int m = 0; m < 4; m++)
                #pragma unroll
                for (int n = 0; n < 4; n++)
                    acc[m][n] = __builtin_amdgcn_mfma_f32_16x16x32_bf16(af[m], bf[n], acc[m][n], 0, 0, 0);
        }

        int mode = mask_mode(att_raw);
        bool mk[4];
        #pragma unroll
        for (int n = 0; n < 4; n++) {
            int t = t0 + wc * 64 + n * 16 + (lane & 15);
            mk[n] = get_mask(dtm_raw, b * (2 * LL) + LL + t, mode);
        }
        #pragma unroll
        for (int m = 0; m < 4; m++) {
            #pragma unroll
            for (int reg = 0; reg < 4; reg++) {
                float s = 0.0f;
                #pragma unroll
                for (int n = 0; n < 4; n++)
                    s += mk[n] ? __expf(acc[m][n][reg] * INV_TEMP) : 0.0f;
                #pragma unroll
                for (int off = 1; off < 16; off <<= 1) s += __shfl_xor(s, off);
                if ((lane & 15) == 0) {
                    int l = l0 + wr * 64 + m * 16 + (lane >> 4) * 4 + reg;
                    ws[WS_DENP + (b * LL + l) * 8 + ttile] = s;
                }
            }
        }
        return;
    }

    float (*part)[2] = (float(*)[2])As;   // reuse den's LDS for block partials

    if (r <= 4) {
        // ---------------- cls: row softmax over V=64 ----------------
        int cb   = g * 4 + (r - 1);
        int row  = cb * 4 + wv;
        float x  = logits[(size_t)row * VV + lane];
        float mx = wave_red_max(x);
        float se = wave_red_sum(__expf(x - mx));
        float sx = wave_red_sum(x);
        float logZ = mx + logf(se);
        int t = tok[row];
        float xt = __shfl(x, t);
        float per = 0.9f * (logZ - xt) + 0.1f * (logZ - sx * (1.0f / VV));
        bool valid = (t > 3);
        if (lane == 0) {
            part[wv][0] = valid ? per : 0.0f;
            part[wv][1] = valid ? 1.0f : 0.0f;
        }
        __syncthreads();
        if (tid == 0) {
            ws[WS_CLS + cb * 2 + 0] = part[0][0] + part[1][0] + part[2][0] + part[3][0];
            ws[WS_CLS + cb * 2 + 1] = part[0][1] + part[1][1] + part[2][1] + part[3][1];
        }
        return;
    }

    if (r <= 12) {
        // ---------------- span contrastive, single fused pass ----------------
        int cb   = g * 8 + (r - 5);       // 0..4095
        int gw   = cb * 4 + wv;
        int mat  = gw >> 13;
        int row  = gw & 8191;
        int j    = row & 1023;
        const float* sim  = (mat ? col_sim  : row_sim)  + (size_t)row * LL;
        const float* coef = (mat ? col_coef : row_coef) + (size_t)row * LL;

        float4 v[4], c[4];
        #pragma unroll
        for (int e = 0; e < 4; e++) v[e] = ((const float4*)sim)[e * 64 + lane];
        #pragma unroll
        for (int e = 0; e < 4; e++) c[e] = ((const float4*)coef)[e * 64 + lane];

        float se = 0.0f, diag = 0.0f, sw = 0.0f, sws = 0.0f;
        #pragma unroll
        for (int e = 0; e < 4; e++) {
            float xs[4] = {v[e].x, v[e].y, v[e].z, v[e].w};
            float cs[4] = {c[e].x, c[e].y, c[e].z, c[e].w};
            #pragma unroll
            for (int q = 0; q < 4; q++) {
                float s  = xs[q] * INV_TEMP;
                float es = __expf(s);
                se += es;
                if (e * 256 + lane * 4 + q == j) diag = es;
                float w = cs[q] > 0.0f ? cs[q] : 0.0f;
                sw  += w;
                sws += w * s;
            }
        }
        #pragma unroll
        for (int off = 32; off; off >>= 1) {
            se   += __shfl_xor(se,   off);
            diag += __shfl_xor(diag, off);
            sw   += __shfl_xor(sw,   off);
            sws  += __shfl_xor(sws,  off);
        }
        float logden = logf(se - diag + EPSF);
        bool hp = sw > 0.0f;
        float loss = (logden * sw - sws) / (sw + EPSF);
        if (lane == 0) {
            part[wv][0] = hp ? loss : 0.0f;
            part[wv][1] = hp ? 1.0f : 0.0f;
        }
        __syncthreads();
        if (tid == 0) {
            ws[WS_CONTR + cb * 2 + 0] = part[0][0] + part[1][0] + part[2][0] + part[3][0];
            ws[WS_CONTR + cb * 2 + 1] = part[0][1] + part[1][1] + part[2][1] + part[3][1];
        }
        return;
    }

    if (r <= 16) {
        // ---------------- empty pointer BCE ----------------
        int eb   = g * 4 + (r - 13);
        int row  = eb * 4 + wv;
        int b = row >> 10, t = row & 1023;
        int mode = mask_mode(att_raw);
        bool att = get_mask(att_raw, b * (2 * LL) + LL + t, mode);   // wave-uniform
        float bce = 0.0f, acnt = 0.0f;
        if (att) {
            const float4* ep = (const float4*)(emptyp + (size_t)b * DD + lane * 8);
            const float4* tp = (const float4*)(tag + (size_t)row * DD + lane * 8);
            float4 e0 = ep[0], e1 = ep[1], y0 = tp[0], y1 = tp[1];
            float d = e0.x * y0.x + e0.y * y0.y + e0.z * y0.z + e0.w * y0.w
                    + e1.x * y1.x + e1.y * y1.y + e1.z * y1.z + e1.w * y1.w;
            d = wave_red_sum(d);
            bool dtm = get_mask(dtm_raw, b * (2 * LL) + LL + t, mode);
            float tgt = dtm ? 0.0f : 1.0f;
            float sp  = fmaxf(d, 0.0f) + log1pf(expf(-fabsf(d)));
            bce = sp - d * tgt;
            acnt = 1.0f;
        }
        if (lane == 0) { part[wv][0] = bce; part[wv][1] = acnt; }
        __syncthreads();
        if (tid == 0) {
            ws[WS_EMP + eb * 2 + 0] = part[0][0] + part[1][0] + part[2][0] + part[3][0];
            ws[WS_EMP + eb * 2 + 1] = part[0][1] + part[1][1] + part[2][1] + part[3][1];
        }
        return;
    }

    // ---------------- ptr: per-row {sum of dots, count} (den-independent) ----
    {
        int pb   = g * 4 + (r - 17);
        int row  = pb * 4 + wv;          // b*L + l
        int b = row >> 10;
        int mode = mask_mode(att_raw);
        const float4* bp = (const float4*)(box + (size_t)row * DD + lane * 8);
        float4 x0 = bp[0], x1 = bp[1];
        float sumd = 0.0f, cnt = 0.0f;
        bool running = true;
        for (int k = 0; k < KK; k++) {
            int idx = bidx[row * KK + k];
            running = running && (idx != -1);
            int rel  = idx - LL;
            int relc = min(max(rel, 0), LL - 1);
            bool dg = get_mask(dtm_raw, b * (2 * LL) + LL + relc, mode);
            bool m = running && dg;
            if (m) {
                const float4* tp = (const float4*)(tag + ((size_t)b * LL + relc) * DD + lane * 8);
                float4 y0 = tp[0], y1 = tp[1];
                float d = x0.x * y0.x + x0.y * y0.y + x0.z * y0.z + x0.w * y0.w
                        + x1.x * y1.x + x1.y * y1.y + x1.z * y1.z + x1.w * y1.w;
                d = wave_red_sum(d);
                sumd += d;
                cnt  += 1.0f;
            }
        }
        if (lane == 0) {
            ws[WS_PTRROW + row * 2 + 0] = sumd;
            ws[WS_PTRROW + row * 2 + 1] = cnt;
        }
    }
}

// ================= final combine: row log-coupling + tree reduce ============
// q: 0 cls_s,1 cls_c,2 ptr_s,3 ptr_c,4 row_s,5 row_c,6 col_s,7 col_c,
//    8 e0s,9 e0c,10 e1s,11 e1c
__global__ __launch_bounds__(1024) void k_final(const float* __restrict__ ws, float* __restrict__ out) {
    __shared__ float red[16][12];
    int tid  = threadIdx.x;
    int lane = tid & 63, wv = tid >> 6;

    float q[12];
    #pragma unroll
    for (int i = 0; i < 12; i++) q[i] = 0.0f;

    // ptr: per-row cnt*log(den)+(-10*sumd), 8 rows per thread
    #pragma unroll
    for (int i = 0; i < 8; i++) {
        int row = tid * 8 + i;
        const float* dp = ws + WS_DENP + (size_t)row * 8;
        float4 d0 = *(const float4*)dp;
        float4 d1 = *(const float4*)(dp + 4);
        float den = d0.x + d0.y + d0.z + d0.w + d1.x + d1.y + d1.z + d1.w;
        float sumd = ws[WS_PTRROW + row * 2 + 0];
        float cnt  = ws[WS_PTRROW + row * 2 + 1];
        q[2] += cnt * logf(den + EPSF) - INV_TEMP * sumd;
        q[3] += cnt;
    }
    // cls: 2048 pairs
    #pragma unroll
    for (int it = 0; it < 2; it++) {
        int i = tid + it * 1024;
        q[0] += ws[WS_CLS + 2 * i];  q[1] += ws[WS_CLS + 2 * i + 1];
    }
    // contr: 4096 pairs; first 2048 row, last 2048 col
    q[4] = ws[WS_CONTR + 2 * tid]              + ws[WS_CONTR + 2 * (tid + 1024)];
    q[5] = ws[WS_CONTR + 2 * tid + 1]          + ws[WS_CONTR + 2 * (tid + 1024) + 1];
    q[6] = ws[WS_CONTR + 2 * (tid + 2048)]     + ws[WS_CONTR + 2 * (tid + 3072)];
    q[7] = ws[WS_CONTR + 2 * (tid + 2048) + 1] + ws[WS_CONTR + 2 * (tid + 3072) + 1];
    // empty: 2048 pairs; slot i has b = i>>8
    q[8]  = ws[WS_EMP + 2 * tid];
    q[9]  = ws[WS_EMP + 2 * tid + 1];
    q[10] = ws[WS_EMP + 2 * (tid + 1024)];
    q[11] = ws[WS_EMP + 2 * (tid + 1024) + 1];

    #pragma unroll
    for (int i = 0; i < 12; i++) {
        #pragma unroll
        for (int off = 32; off; off >>= 1) q[i] += __shfl_xor(q[i], off);
    }
    if (lane == 0) {
        #pragma unroll
        for (int i = 0; i < 12; i++) red[wv][i] = q[i];
    }
    __syncthreads();
    if (tid == 0) {
        float s[8];
        #pragma unroll
        for (int i = 0; i < 8; i++) s[i] = 0.0f;
        float es[8], ec[8];
        #pragma unroll
        for (int i = 0; i < 8; i++) { es[i] = 0.0f; ec[i] = 0.0f; }
        #pragma unroll
        for (int w = 0; w < 16; w++) {
            #pragma unroll
            for (int i = 0; i < 8; i++) s[i] += red[w][i];
            es[(w >> 2)]     += red[w][8];
            ec[(w >> 2)]     += red[w][9];
            es[(w >> 2) + 4] += red[w][10];
            ec[(w >> 2) + 4] += red[w][11];
        }
        float cls = s[0] / fmaxf(s[1], 1.0f);
        float ptr = (s[3] > 0.0f) ? s[2] / fmaxf(s[3], 1.0f) : 0.0f;
        float emp = 0.0f;
        #pragma unroll
        for (int b = 0; b < 8; b++) emp += es[b] / fmaxf(ec[b], 1.0f);
        emp *= (1.0f / BB);
        float rc = (s[5] > 0.0f) ? s[4] / fmaxf(s[5], 1.0f) : 0.0f;
        float cc = (s[7] > 0.0f) ? s[6] / fmaxf(s[7], 1.0f) : 0.0f;
        float tot = cls + ptr + emp + 0.5f * (rc + cc);
        out[0] = tot; out[1] = cls; out[2] = ptr;
        out[3] = emp; out[4] = rc;  out[5] = cc;
    }
}

extern "C" void kernel_launch(void* const* d_in, const int* in_sizes, int n_in,
                              void* d_out, int out_size, void* d_ws, size_t ws_size,
                              hipStream_t stream) {
    (void)in_sizes; (void)n_in; (void)out_size; (void)ws_size;
    const int*   token_ids = (const int*)  d_in[0];
    const int*   box_idx   = (const int*)  d_in[1];
    const void*  dtm       =               d_in[2];
    const void*  att       =               d_in[3];
    const float* tag_log   = (const float*)d_in[4];
    const float* box_proj  = (const float*)d_in[5];
    const float* tag_proj  = (const float*)d_in[6];
    const float* empty_p   = (const float*)d_in[7];
    const float* row_sim   = (const float*)d_in[8];
    const float* col_sim   = (const float*)d_in[9];
    const float* row_coef  = (const float*)d_in[10];
    const float* col_coef  = (const float*)d_in[11];
    float* ws  = (float*)d_ws;
    float* out = (float*)d_out;

    // one fused launch for all independent work, then the combine
    k_mega <<<512 * 21, 256, 0, stream>>>(box_proj, tag_proj, tag_log, token_ids,
                                          box_idx, empty_p, row_sim, col_sim,
                                          row_coef, col_coef, dtm, att, ws);
    k_final<<<1, 1024, 0, stream>>>(ws, out);
}

// Round 8
// 87.045 us; speedup vs baseline: 1.1139x; 1.1139x over previous
//
#include <hip/hip_runtime.h>
#include <hip/hip_bf16.h>
#include <math.h>

#define BB 8
#define LL 1024
#define DD 512
#define VV 64
#define KK 8

constexpr float INV_TEMP = 10.0f;   // 1/TEMP
constexpr float EPSF     = 1e-10f;

// ---------------- workspace float layout (NO atomics, NO memset) ------------
#define WS_DENP   0                       // den partials [8192][8]
#define WS_CLS    (8192*8)                // cls  per-block {sum,cnt} x 2048
#define WS_EMP    (WS_CLS + 4096)         // emp  per-block {sum,cnt} x 2048
#define WS_CONTR  (WS_EMP + 4096)         // contr {sum,cnt} x 4096 (row:0-2047, col:2048-4095)
#define WS_PTRROW (WS_CONTR + 8192)       // ptr per-row {sumd,cnt} x 8192

typedef __attribute__((ext_vector_type(8))) short  short8;
typedef __attribute__((ext_vector_type(4))) float  f32x4;

// ---------------- bool-dtype detection ----------------
// MUST be fed attention_mask: its first L entries are all-True by construction.
__device__ __forceinline__ int mask_mode(const void* att_raw) {
    const unsigned* w = (const unsigned*)att_raw;
    unsigned w0 = w[0];
    if (w0 == 0x01010101u) return 0;           // bool/uint8
    if (w0 == 0x3f800000u) return 2;           // float32
    if (w0 == 1u) return (w[1] == 0u) ? 3 : 1; // int64 : int32
    return 0;
}
__device__ __forceinline__ bool get_mask(const void* p, int idx, int mode) {
    if (mode == 0) return ((const unsigned char*)p)[idx] != 0;
    if (mode == 1) return ((const int*)p)[idx] != 0;
    if (mode == 3) return ((const unsigned*)p)[2*idx] != 0u;
    return ((const float*)p)[idx] != 0.0f;
}

__device__ __forceinline__ float wave_red_sum(float v) {
    #pragma unroll
    for (int off = 32; off; off >>= 1) v += __shfl_xor(v, off);
    return v;
}
__device__ __forceinline__ float wave_red_max(float v) {
    #pragma unroll
    for (int off = 32; off; off >>= 1) v = fmaxf(v, __shfl_xor(v, off));
    return v;
}

__device__ __forceinline__ short bfb(float f) {
    __hip_bfloat16 h = __float2bfloat16(f);
    union { __hip_bfloat16 h; short u; } c; c.h = h; return c.u;
}

#define BM 128
#define BKD 32
#define ST 40            // LDS row stride in shorts (80 bytes)

// ================= den: bf16 MFMA GEMM + masked exp row-sum (unchanged) =====
__global__ __launch_bounds__(256) void k_den(const float* __restrict__ box,
                                             const float* __restrict__ tag,
                                             const void* __restrict__ dtm_raw,
                                             const void* __restrict__ att_raw,
                                             float* __restrict__ ws) {
    __shared__ short As[BM * ST];
    __shared__ short Bs[BM * ST];

    int bid   = blockIdx.x;
    int b     = bid & 7;
    int tile  = bid >> 3;
    int l0    = (tile >> 3) * BM;
    int ttile = tile & 7;
    int t0    = ttile * BM;

    int tid  = threadIdx.x;
    int lane = tid & 63;
    int wave = tid >> 6;
    int wr   = wave >> 1, wc = wave & 1;

    int srow  = tid >> 1;
    int shalf = tid & 1;
    const float* gA = box + ((size_t)b * LL + l0 + srow) * DD + shalf * 16;
    const float* gB = tag + ((size_t)b * LL + t0 + srow) * DD + shalf * 16;
    short* wA = &As[srow * ST + shalf * 16];
    short* wB = &Bs[srow * ST + shalf * 16];

    f32x4 acc[4][4];
    #pragma unroll
    for (int m = 0; m < 4; m++)
        #pragma unroll
        for (int n = 0; n < 4; n++) acc[m][n] = (f32x4){0.f, 0.f, 0.f, 0.f};

    int k0 = (lane >> 4) * 8;
    const short* rA = &As[(wr * 64 + (lane & 15)) * ST + k0];
    const short* rB = &Bs[(wc * 64 + (lane & 15)) * ST + k0];

    for (int d0 = 0; d0 < DD; d0 += BKD) {
        __syncthreads();
        float4 fa0 = *(const float4*)(gA + d0);
        float4 fa1 = *(const float4*)(gA + d0 + 4);
        float4 fa2 = *(const float4*)(gA + d0 + 8);
        float4 fa3 = *(const float4*)(gA + d0 + 12);
        float4 fb0 = *(const float4*)(gB + d0);
        float4 fb1 = *(const float4*)(gB + d0 + 4);
        float4 fb2 = *(const float4*)(gB + d0 + 8);
        float4 fb3 = *(const float4*)(gB + d0 + 12);
        short8 va0 = {bfb(fa0.x), bfb(fa0.y), bfb(fa0.z), bfb(fa0.w),
                      bfb(fa1.x), bfb(fa1.y), bfb(fa1.z), bfb(fa1.w)};
        short8 va1 = {bfb(fa2.x), bfb(fa2.y), bfb(fa2.z), bfb(fa2.w),
                      bfb(fa3.x), bfb(fa3.y), bfb(fa3.z), bfb(fa3.w)};
        short8 vb0 = {bfb(fb0.x), bfb(fb0.y), bfb(fb0.z), bfb(fb0.w),
                      bfb(fb1.x), bfb(fb1.y), bfb(fb1.z), bfb(fb1.w)};
        short8 vb1 = {bfb(fb2.x), bfb(fb2.y), bfb(fb2.z), bfb(fb2.w),
                      bfb(fb3.x), bfb(fb3.y), bfb(fb3.z), bfb(fb3.w)};
        *(short8*)wA       = va0;
        *(short8*)(wA + 8) = va1;
        *(short8*)wB       = vb0;
        *(short8*)(wB + 8) = vb1;
        __syncthreads();

        short8 af[4], bf[4];
        #pragma unroll
        for (int m = 0; m < 4; m++) af[m] = *(const short8*)(rA + m * 16 * ST);
        #pragma unroll
        for (int n = 0; n < 4; n++) bf[n] = *(const short8*)(rB + n * 16 * ST);
        #pragma unroll
        for (int m = 0; m < 4; m++)
            #pragma unroll
            for (int n = 0; n < 4; n++)
                acc[m][n] = __builtin_amdgcn_mfma_f32_16x16x32_bf16(af[m], bf[n], acc[m][n], 0, 0, 0);
    }

    int mode = mask_mode(att_raw);
    bool mk[4];
    #pragma unroll
    for (int n = 0; n < 4; n++) {
        int t = t0 + wc * 64 + n * 16 + (lane & 15);
        mk[n] = get_mask(dtm_raw, b * (2 * LL) + LL + t, mode);
    }
    #pragma unroll
    for (int m = 0; m < 4; m++) {
        #pragma unroll
        for (int reg = 0; reg < 4; reg++) {
            float s = 0.0f;
            #pragma unroll
            for (int n = 0; n < 4; n++)
                s += mk[n] ? __expf(acc[m][n][reg] * INV_TEMP) : 0.0f;
            #pragma unroll
            for (int off = 1; off < 16; off <<= 1) s += __shfl_xor(s, off);
            if ((lane & 15) == 0) {
                int l = l0 + wr * 64 + m * 16 + (lane >> 4) * 4 + reg;
                ws[WS_DENP + (b * LL + l) * 8 + ttile] = s;
            }
        }
    }
}

// ================= light kernel: contr + ptr + empty + cls, VGPR<=64 ========
// grid 8192: contr [0,2048) | ptr [2048,4096) | empty [4096,6144) | cls [6144,8192)
__global__ __launch_bounds__(256, 8) void k_light(
        const float* __restrict__ box,     const float* __restrict__ tag,
        const float* __restrict__ logits,  const int* __restrict__ tok,
        const int* __restrict__ bidx,      const float* __restrict__ emptyp,
        const float* __restrict__ row_sim, const float* __restrict__ col_sim,
        const float* __restrict__ row_coef,const float* __restrict__ col_coef,
        const void* __restrict__ dtm_raw,  const void* __restrict__ att_raw,
        float* __restrict__ ws) {
    __shared__ float part[4][4];
    int bid  = blockIdx.x;
    int tid  = threadIdx.x;
    int lane = tid & 63;
    int wv   = tid >> 6;

    if (bid < 2048) {
        // ---- span contrastive: one wave handles row gw of BOTH matrices ----
        int gw = bid * 4 + wv;            // 0..8191 (b*L + j)
        int j  = gw & 1023;
        const float* sim0 = row_sim  + (size_t)gw * LL;
        const float* cf0  = row_coef + (size_t)gw * LL;
        const float* sim1 = col_sim  + (size_t)gw * LL;
        const float* cf1  = col_coef + (size_t)gw * LL;

        // 16 vector loads + 2 uniform diag loads issued up front (max MLP)
        float4 v0[4], c0[4], v1[4], c1[4];
        #pragma unroll
        for (int e = 0; e < 4; e++) v0[e] = ((const float4*)sim0)[e * 64 + lane];
        #pragma unroll
        for (int e = 0; e < 4; e++) v1[e] = ((const float4*)sim1)[e * 64 + lane];
        #pragma unroll
        for (int e = 0; e < 4; e++) c0[e] = ((const float4*)cf0)[e * 64 + lane];
        #pragma unroll
        for (int e = 0; e < 4; e++) c1[e] = ((const float4*)cf1)[e * 64 + lane];
        float d0v = sim0[j], d1v = sim1[j];

        float se0 = 0.f, sw0 = 0.f, sws0 = 0.f;
        float se1 = 0.f, sw1 = 0.f, sws1 = 0.f;
        #pragma unroll
        for (int e = 0; e < 4; e++) {
            float xs[4] = {v0[e].x, v0[e].y, v0[e].z, v0[e].w};
            float cs[4] = {c0[e].x, c0[e].y, c0[e].z, c0[e].w};
            #pragma unroll
            for (int q = 0; q < 4; q++) {
                float s = xs[q] * INV_TEMP;
                se0 += __expf(s);
                float w = cs[q] > 0.0f ? cs[q] : 0.0f;
                sw0 += w; sws0 += w * s;
            }
        }
        #pragma unroll
        for (int e = 0; e < 4; e++) {
            float xs[4] = {v1[e].x, v1[e].y, v1[e].z, v1[e].w};
            float cs[4] = {c1[e].x, c1[e].y, c1[e].z, c1[e].w};
            #pragma unroll
            for (int q = 0; q < 4; q++) {
                float s = xs[q] * INV_TEMP;
                se1 += __expf(s);
                float w = cs[q] > 0.0f ? cs[q] : 0.0f;
                sw1 += w; sws1 += w * s;
            }
        }
        // 6 independent butterfly chains
        #pragma unroll
        for (int off = 32; off; off >>= 1) {
            se0  += __shfl_xor(se0,  off);
            sw0  += __shfl_xor(sw0,  off);
            sws0 += __shfl_xor(sws0, off);
            se1  += __shfl_xor(se1,  off);
            sw1  += __shfl_xor(sw1,  off);
            sws1 += __shfl_xor(sws1, off);
        }
        float logden0 = logf(se0 - __expf(d0v * INV_TEMP) + EPSF);
        float logden1 = logf(se1 - __expf(d1v * INV_TEMP) + EPSF);
        bool hp0 = sw0 > 0.0f, hp1 = sw1 > 0.0f;
        float loss0 = (logden0 * sw0 - sws0) / (sw0 + EPSF);
        float loss1 = (logden1 * sw1 - sws1) / (sw1 + EPSF);
        if (lane == 0) {
            part[wv][0] = hp0 ? loss0 : 0.0f;
            part[wv][1] = hp0 ? 1.0f : 0.0f;
            part[wv][2] = hp1 ? loss1 : 0.0f;
            part[wv][3] = hp1 ? 1.0f : 0.0f;
        }
        __syncthreads();
        if (tid == 0) {
            ws[WS_CONTR + bid * 2 + 0] = part[0][0] + part[1][0] + part[2][0] + part[3][0];
            ws[WS_CONTR + bid * 2 + 1] = part[0][1] + part[1][1] + part[2][1] + part[3][1];
            ws[WS_CONTR + (2048 + bid) * 2 + 0] = part[0][2] + part[1][2] + part[2][2] + part[3][2];
            ws[WS_CONTR + (2048 + bid) * 2 + 1] = part[0][3] + part[1][3] + part[2][3] + part[3][3];
        }
        return;
    }

    if (bid < 4096) {
        // ---- ptr: per-row {sum of dots, count} ----
        int row = (bid - 2048) * 4 + wv;     // b*L + l
        int b = row >> 10;
        int mode = mask_mode(att_raw);
        const float4* bp = (const float4*)(box + (size_t)row * DD + lane * 8);
        float4 x0 = bp[0], x1 = bp[1];
        float sumd = 0.0f, cnt = 0.0f;
        bool running = true;
        for (int k = 0; k < KK; k++) {
            int idx = bidx[row * KK + k];
            running = running && (idx != -1);
            int rel  = idx - LL;
            int relc = min(max(rel, 0), LL - 1);
            bool dg = get_mask(dtm_raw, b * (2 * LL) + LL + relc, mode);
            bool m = running && dg;
            if (m) {
                const float4* tp = (const float4*)(tag + ((size_t)b * LL + relc) * DD + lane * 8);
                float4 y0 = tp[0], y1 = tp[1];
                float d = x0.x * y0.x + x0.y * y0.y + x0.z * y0.z + x0.w * y0.w
                        + x1.x * y1.x + x1.y * y1.y + x1.z * y1.z + x1.w * y1.w;
                d = wave_red_sum(d);
                sumd += d;
                cnt  += 1.0f;
            }
        }
        if (lane == 0) {
            ws[WS_PTRROW + row * 2 + 0] = sumd;
            ws[WS_PTRROW + row * 2 + 1] = cnt;
        }
        return;
    }

    if (bid < 6144) {
        // ---- empty pointer BCE ----
        int eb  = bid - 4096;
        int row = eb * 4 + wv;               // b*L + t
        int b = row >> 10, t = row & 1023;
        int mode = mask_mode(att_raw);
        bool att = get_mask(att_raw, b * (2 * LL) + LL + t, mode);   // wave-uniform
        float bce = 0.0f, acnt = 0.0f;
        if (att) {
            const float4* ep = (const float4*)(emptyp + (size_t)b * DD + lane * 8);
            const float4* tp = (const float4*)(tag + (size_t)row * DD + lane * 8);
            float4 e0 = ep[0], e1 = ep[1], y0 = tp[0], y1 = tp[1];
            float d = e0.x * y0.x + e0.y * y0.y + e0.z * y0.z + e0.w * y0.w
                    + e1.x * y1.x + e1.y * y1.y + e1.z * y1.z + e1.w * y1.w;
            d = wave_red_sum(d);
            bool dtm = get_mask(dtm_raw, b * (2 * LL) + LL + t, mode);
            float tgt = dtm ? 0.0f : 1.0f;
            float sp  = fmaxf(d, 0.0f) + log1pf(expf(-fabsf(d)));
            bce = sp - d * tgt;
            acnt = 1.0f;
        }
        if (lane == 0) { part[wv][0] = bce; part[wv][1] = acnt; }
        __syncthreads();
        if (tid == 0) {
            ws[WS_EMP + eb * 2 + 0] = part[0][0] + part[1][0] + part[2][0] + part[3][0];
            ws[WS_EMP + eb * 2 + 1] = part[0][1] + part[1][1] + part[2][1] + part[3][1];
        }
        return;
    }

    {
        // ---- cls: row softmax over V=64 ----
        int cb  = bid - 6144;
        int row = cb * 4 + wv;
        float x  = logits[(size_t)row * VV + lane];
        float mx = wave_red_max(x);
        float se = wave_red_sum(__expf(x - mx));
        float sx = wave_red_sum(x);
        float logZ = mx + logf(se);
        int t = tok[row];
        float xt = __shfl(x, t);
        float per = 0.9f * (logZ - xt) + 0.1f * (logZ - sx * (1.0f / VV));
        bool valid = (t > 3);
        if (lane == 0) {
            part[wv][0] = valid ? per : 0.0f;
            part[wv][1] = valid ? 1.0f : 0.0f;
        }
        __syncthreads();
        if (tid == 0) {
            ws[WS_CLS + cb * 2 + 0] = part[0][0] + part[1][0] + part[2][0] + part[3][0];
            ws[WS_CLS + cb * 2 + 1] = part[0][1] + part[1][1] + part[2][1] + part[3][1];
        }
    }
}

// ================= final combine: row log-coupling + tree reduce ============
__global__ __launch_bounds__(1024) void k_final(const float* __restrict__ ws, float* __restrict__ out) {
    __shared__ float red[16][12];
    int tid  = threadIdx.x;
    int lane = tid & 63, wv = tid >> 6;

    float q[12];
    #pragma unroll
    for (int i = 0; i < 12; i++) q[i] = 0.0f;

    // ptr: per-row cnt*log(den) - 10*sumd, 8 rows per thread
    #pragma unroll
    for (int i = 0; i < 8; i++) {
        int row = tid * 8 + i;
        const float* dp = ws + WS_DENP + (size_t)row * 8;
        float4 d0 = *(const float4*)dp;
        float4 d1 = *(const float4*)(dp + 4);
        float den = d0.x + d0.y + d0.z + d0.w + d1.x + d1.y + d1.z + d1.w;
        float sumd = ws[WS_PTRROW + row * 2 + 0];
        float cnt  = ws[WS_PTRROW + row * 2 + 1];
        q[2] += cnt * logf(den + EPSF) - INV_TEMP * sumd;
        q[3] += cnt;
    }
    #pragma unroll
    for (int it = 0; it < 2; it++) {
        int i = tid + it * 1024;
        q[0] += ws[WS_CLS + 2 * i];  q[1] += ws[WS_CLS + 2 * i + 1];
    }
    q[4] = ws[WS_CONTR + 2 * tid]              + ws[WS_CONTR + 2 * (tid + 1024)];
    q[5] = ws[WS_CONTR + 2 * tid + 1]          + ws[WS_CONTR + 2 * (tid + 1024) + 1];
    q[6] = ws[WS_CONTR + 2 * (tid + 2048)]     + ws[WS_CONTR + 2 * (tid + 3072)];
    q[7] = ws[WS_CONTR + 2 * (tid + 2048) + 1] + ws[WS_CONTR + 2 * (tid + 3072) + 1];
    q[8]  = ws[WS_EMP + 2 * tid];
    q[9]  = ws[WS_EMP + 2 * tid + 1];
    q[10] = ws[WS_EMP + 2 * (tid + 1024)];
    q[11] = ws[WS_EMP + 2 * (tid + 1024) + 1];

    #pragma unroll
    for (int i = 0; i < 12; i++) {
        #pragma unroll
        for (int off = 32; off; off >>= 1) q[i] += __shfl_xor(q[i], off);
    }
    if (lane == 0) {
        #pragma unroll
        for (int i = 0; i < 12; i++) red[wv][i] = q[i];
    }
    __syncthreads();
    if (tid == 0) {
        float s[8];
        #pragma unroll
        for (int i = 0; i < 8; i++) s[i] = 0.0f;
        float es[8], ec[8];
        #pragma unroll
        for (int i = 0; i < 8; i++) { es[i] = 0.0f; ec[i] = 0.0f; }
        #pragma unroll
        for (int w = 0; w < 16; w++) {
            #pragma unroll
            for (int i = 0; i < 8; i++) s[i] += red[w][i];
            es[(w >> 2)]     += red[w][8];
            ec[(w >> 2)]     += red[w][9];
            es[(w >> 2) + 4] += red[w][10];
            ec[(w >> 2) + 4] += red[w][11];
        }
        float cls = s[0] / fmaxf(s[1], 1.0f);
        float ptr = (s[3] > 0.0f) ? s[2] / fmaxf(s[3], 1.0f) : 0.0f;
        float emp = 0.0f;
        #pragma unroll
        for (int b = 0; b < 8; b++) emp += es[b] / fmaxf(ec[b], 1.0f);
        emp *= (1.0f / BB);
        float rc = (s[5] > 0.0f) ? s[4] / fmaxf(s[5], 1.0f) : 0.0f;
        float cc = (s[7] > 0.0f) ? s[6] / fmaxf(s[7], 1.0f) : 0.0f;
        float tot = cls + ptr + emp + 0.5f * (rc + cc);
        out[0] = tot; out[1] = cls; out[2] = ptr;
        out[3] = emp; out[4] = rc;  out[5] = cc;
    }
}

extern "C" void kernel_launch(void* const* d_in, const int* in_sizes, int n_in,
                              void* d_out, int out_size, void* d_ws, size_t ws_size,
                              hipStream_t stream) {
    (void)in_sizes; (void)n_in; (void)out_size; (void)ws_size;
    const int*   token_ids = (const int*)  d_in[0];
    const int*   box_idx   = (const int*)  d_in[1];
    const void*  dtm       =               d_in[2];
    const void*  att       =               d_in[3];
    const float* tag_log   = (const float*)d_in[4];
    const float* box_proj  = (const float*)d_in[5];
    const float* tag_proj  = (const float*)d_in[6];
    const float* empty_p   = (const float*)d_in[7];
    const float* row_sim   = (const float*)d_in[8];
    const float* col_sim   = (const float*)d_in[9];
    const float* row_coef  = (const float*)d_in[10];
    const float* col_coef  = (const float*)d_in[11];
    float* ws  = (float*)d_ws;
    float* out = (float*)d_out;

    k_den  <<<BB * 64, 256, 0, stream>>>(box_proj, tag_proj, dtm, att, ws);
    k_light<<<8192, 256, 0, stream>>>(box_proj, tag_proj, tag_log, token_ids,
                                      box_idx, empty_p, row_sim, col_sim,
                                      row_coef, col_coef, dtm, att, ws);
    k_final<<<1, 1024, 0, stream>>>(ws, out);
}

// Round 9
// 84.830 us; speedup vs baseline: 1.1430x; 1.0261x over previous
//
#include <hip/hip_runtime.h>
#include <hip/hip_bf16.h>
#include <math.h>

#define BB 8
#define LL 1024
#define DD 512
#define VV 64
#define KK 8

constexpr float INV_TEMP = 10.0f;   // 1/TEMP
constexpr float EPSF     = 1e-10f;

// ---------------- workspace float layout (NO atomics, NO memset) ------------
#define WS_DENP   0                       // den partials [8192][8]
#define WS_CLS    (8192*8)                // cls  per-block {sum,cnt} x 2048
#define WS_EMP    (WS_CLS + 4096)         // emp  per-block {sum,cnt} x 2048
#define WS_CONTR  (WS_EMP + 4096)         // contr {sum,cnt} x 2048 (mat0:0-1023, mat1:1024-2047)
#define WS_PTRROW (WS_CONTR + 8192)       // ptr per-row {sumd,cnt} x 8192

typedef __attribute__((ext_vector_type(8))) short  short8;
typedef __attribute__((ext_vector_type(4))) float  f32x4;

typedef __attribute__((address_space(1))) const void GV;
typedef __attribute__((address_space(3))) void LV;
__device__ __forceinline__ void gload16(const void* g, void* l) {
    // DMA 16B/lane global->LDS; LDS dest = wave-uniform base + lane*16
    __builtin_amdgcn_global_load_lds((GV*)g, (LV*)l, 16, 0, 0);
}

// ---------------- bool-dtype detection ----------------
// MUST be fed attention_mask: its first L entries are all-True by construction.
__device__ __forceinline__ int mask_mode(const void* att_raw) {
    const unsigned* w = (const unsigned*)att_raw;
    unsigned w0 = w[0];
    if (w0 == 0x01010101u) return 0;           // bool/uint8
    if (w0 == 0x3f800000u) return 2;           // float32
    if (w0 == 1u) return (w[1] == 0u) ? 3 : 1; // int64 : int32
    return 0;
}
__device__ __forceinline__ bool get_mask(const void* p, int idx, int mode) {
    if (mode == 0) return ((const unsigned char*)p)[idx] != 0;
    if (mode == 1) return ((const int*)p)[idx] != 0;
    if (mode == 3) return ((const unsigned*)p)[2*idx] != 0u;
    return ((const float*)p)[idx] != 0.0f;
}

__device__ __forceinline__ float wave_red_sum(float v) {
    #pragma unroll
    for (int off = 32; off; off >>= 1) v += __shfl_xor(v, off);
    return v;
}
__device__ __forceinline__ float wave_red_max(float v) {
    #pragma unroll
    for (int off = 32; off; off >>= 1) v = fmaxf(v, __shfl_xor(v, off));
    return v;
}

__device__ __forceinline__ short bfb(float f) {
    __hip_bfloat16 h = __float2bfloat16(f);
    union { __hip_bfloat16 h; short u; } c; c.h = h; return c.u;
}

#define BM 128
#define BKD 32
#define ST 40            // LDS row stride in shorts (80 bytes)

// ================= den: bf16 MFMA GEMM + masked exp row-sum (unchanged) =====
__global__ __launch_bounds__(256) void k_den(const float* __restrict__ box,
                                             const float* __restrict__ tag,
                                             const void* __restrict__ dtm_raw,
                                             const void* __restrict__ att_raw,
                                             float* __restrict__ ws) {
    __shared__ short As[BM * ST];
    __shared__ short Bs[BM * ST];

    int bid   = blockIdx.x;
    int b     = bid & 7;
    int tile  = bid >> 3;
    int l0    = (tile >> 3) * BM;
    int ttile = tile & 7;
    int t0    = ttile * BM;

    int tid  = threadIdx.x;
    int lane = tid & 63;
    int wave = tid >> 6;
    int wr   = wave >> 1, wc = wave & 1;

    int srow  = tid >> 1;
    int shalf = tid & 1;
    const float* gA = box + ((size_t)b * LL + l0 + srow) * DD + shalf * 16;
    const float* gB = tag + ((size_t)b * LL + t0 + srow) * DD + shalf * 16;
    short* wA = &As[srow * ST + shalf * 16];
    short* wB = &Bs[srow * ST + shalf * 16];

    f32x4 acc[4][4];
    #pragma unroll
    for (int m = 0; m < 4; m++)
        #pragma unroll
        for (int n = 0; n < 4; n++) acc[m][n] = (f32x4){0.f, 0.f, 0.f, 0.f};

    int k0 = (lane >> 4) * 8;
    const short* rA = &As[(wr * 64 + (lane & 15)) * ST + k0];
    const short* rB = &Bs[(wc * 64 + (lane & 15)) * ST + k0];

    for (int d0 = 0; d0 < DD; d0 += BKD) {
        __syncthreads();
        float4 fa0 = *(const float4*)(gA + d0);
        float4 fa1 = *(const float4*)(gA + d0 + 4);
        float4 fa2 = *(const float4*)(gA + d0 + 8);
        float4 fa3 = *(const float4*)(gA + d0 + 12);
        float4 fb0 = *(const float4*)(gB + d0);
        float4 fb1 = *(const float4*)(gB + d0 + 4);
        float4 fb2 = *(const float4*)(gB + d0 + 8);
        float4 fb3 = *(const float4*)(gB + d0 + 12);
        short8 va0 = {bfb(fa0.x), bfb(fa0.y), bfb(fa0.z), bfb(fa0.w),
                      bfb(fa1.x), bfb(fa1.y), bfb(fa1.z), bfb(fa1.w)};
        short8 va1 = {bfb(fa2.x), bfb(fa2.y), bfb(fa2.z), bfb(fa2.w),
                      bfb(fa3.x), bfb(fa3.y), bfb(fa3.z), bfb(fa3.w)};
        short8 vb0 = {bfb(fb0.x), bfb(fb0.y), bfb(fb0.z), bfb(fb0.w),
                      bfb(fb1.x), bfb(fb1.y), bfb(fb1.z), bfb(fb1.w)};
        short8 vb1 = {bfb(fb2.x), bfb(fb2.y), bfb(fb2.z), bfb(fb2.w),
                      bfb(fb3.x), bfb(fb3.y), bfb(fb3.z), bfb(fb3.w)};
        *(short8*)wA       = va0;
        *(short8*)(wA + 8) = va1;
        *(short8*)wB       = vb0;
        *(short8*)(wB + 8) = vb1;
        __syncthreads();

        short8 af[4], bf[4];
        #pragma unroll
        for (int m = 0; m < 4; m++) af[m] = *(const short8*)(rA + m * 16 * ST);
        #pragma unroll
        for (int n = 0; n < 4; n++) bf[n] = *(const short8*)(rB + n * 16 * ST);
        #pragma unroll
        for (int m = 0; m < 4; m++)
            #pragma unroll
            for (int n = 0; n < 4; n++)
                acc[m][n] = __builtin_amdgcn_mfma_f32_16x16x32_bf16(af[m], bf[n], acc[m][n], 0, 0, 0);
    }

    int mode = mask_mode(att_raw);
    bool mk[4];
    #pragma unroll
    for (int n = 0; n < 4; n++) {
        int t = t0 + wc * 64 + n * 16 + (lane & 15);
        mk[n] = get_mask(dtm_raw, b * (2 * LL) + LL + t, mode);
    }
    #pragma unroll
    for (int m = 0; m < 4; m++) {
        #pragma unroll
        for (int reg = 0; reg < 4; reg++) {
            float s = 0.0f;
            #pragma unroll
            for (int n = 0; n < 4; n++)
                s += mk[n] ? __expf(acc[m][n][reg] * INV_TEMP) : 0.0f;
            #pragma unroll
            for (int off = 1; off < 16; off <<= 1) s += __shfl_xor(s, off);
            if ((lane & 15) == 0) {
                int l = l0 + wr * 64 + m * 16 + (lane >> 4) * 4 + reg;
                ws[WS_DENP + (b * LL + l) * 8 + ttile] = s;
            }
        }
    }
}

// ================= span contrastive via global_load_lds DMA streaming ========
// 1024 blocks x 4 waves; wave (rp,mat) owns a private 8KB LDS region and
// processes rows bid*8 + it*2 + rp of matrix `mat` (sim + coef). No barriers
// in the loop: each wave consumes only what it staged (vmcnt is per-wave).
__global__ __launch_bounds__(256) void k_contr(
        const float* __restrict__ row_sim, const float* __restrict__ col_sim,
        const float* __restrict__ row_coef,const float* __restrict__ col_coef,
        float* __restrict__ ws) {
    __shared__ float cbuf[8192];   // 32 KB: [rp(2)][mat(2)][{sim,cf}(2)][1024]
    int bid  = blockIdx.x;
    int tid  = threadIdx.x;
    int lane = tid & 63;
    int wv   = tid >> 6;
    int rp   = wv >> 1;
    int mat  = wv & 1;
    float* myreg = &cbuf[rp * 4096 + mat * 2048];   // sim [0,1024), cf [1024,2048)
    const float* simsrc = mat ? col_sim  : row_sim;
    const float* cfsrc  = mat ? col_coef : row_coef;

    float acc_sum = 0.0f, acc_cnt = 0.0f;
    for (int it = 0; it < 4; ++it) {
        int row = bid * 8 + it * 2 + rp;           // 0..8191 (b*L + j)
        const float* s = simsrc + (size_t)row * LL;
        const float* c = cfsrc  + (size_t)row * LL;
        #pragma unroll
        for (int ch = 0; ch < 4; ++ch) {
            gload16(s + ch * 256 + lane * 4, myreg + ch * 256);
            gload16(c + ch * 256 + lane * 4, myreg + 1024 + ch * 256);
        }
        asm volatile("s_waitcnt vmcnt(0)" ::: "memory");

        int j = row & 1023;
        float diag = myreg[j];                     // uniform LDS read = broadcast
        float se = 0.0f, sw = 0.0f, sws = 0.0f;
        #pragma unroll
        for (int e = 0; e < 4; ++e) {
            float4 xv = *(const float4*)&myreg[e * 256 + lane * 4];
            float4 cv = *(const float4*)&myreg[1024 + e * 256 + lane * 4];
            float xs[4] = {xv.x, xv.y, xv.z, xv.w};
            float cs[4] = {cv.x, cv.y, cv.z, cv.w};
            #pragma unroll
            for (int q = 0; q < 4; ++q) {
                float sv = xs[q] * INV_TEMP;
                se += __expf(sv);
                float w = cs[q] > 0.0f ? cs[q] : 0.0f;
                sw  += w;
                sws += w * sv;
            }
        }
        #pragma unroll
        for (int off = 32; off; off >>= 1) {
            se  += __shfl_xor(se,  off);
            sw  += __shfl_xor(sw,  off);
            sws += __shfl_xor(sws, off);
        }
        float logden = logf(se - __expf(diag * INV_TEMP) + EPSF);
        bool hp = sw > 0.0f;
        acc_sum += hp ? (logden * sw - sws) / (sw + EPSF) : 0.0f;
        acc_cnt += hp ? 1.0f : 0.0f;
    }
    __syncthreads();                 // all waves done with their regions
    if (lane == 0) { cbuf[wv * 2] = acc_sum; cbuf[wv * 2 + 1] = acc_cnt; }
    __syncthreads();
    if (tid == 0) {
        ws[WS_CONTR + bid * 2 + 0]          = cbuf[0] + cbuf[4];   // mat0: waves 0,2
        ws[WS_CONTR + bid * 2 + 1]          = cbuf[1] + cbuf[5];
        ws[WS_CONTR + (1024 + bid) * 2 + 0] = cbuf[2] + cbuf[6];   // mat1: waves 1,3
        ws[WS_CONTR + (1024 + bid) * 2 + 1] = cbuf[3] + cbuf[7];
    }
}

// ================= rest: ptr+empty merged [0,2048) | cls [2048,4096) ========
__global__ __launch_bounds__(256, 8) void k_rest(
        const float* __restrict__ box,     const float* __restrict__ tag,
        const float* __restrict__ logits,  const int* __restrict__ tok,
        const int* __restrict__ bidx,      const float* __restrict__ emptyp,
        const void* __restrict__ dtm_raw,  const void* __restrict__ att_raw,
        float* __restrict__ ws) {
    __shared__ float part[4][2];
    int bid  = blockIdx.x;
    int tid  = threadIdx.x;
    int lane = tid & 63;
    int wv   = tid >> 6;

    if (bid < 2048) {
        // ---- ptr + empty for row = b*L + i ----
        int row = bid * 4 + wv;
        int b = row >> 10, i = row & 1023;
        int mode = mask_mode(att_raw);

        const float4* tp = (const float4*)(tag + (size_t)row * DD + lane * 8);
        const float4* ep = (const float4*)(emptyp + (size_t)b * DD + lane * 8);
        float4 t0v = tp[0], t1v = tp[1];
        float4 e0  = ep[0], e1  = ep[1];
        float de = e0.x * t0v.x + e0.y * t0v.y + e0.z * t0v.z + e0.w * t0v.w
                 + e1.x * t1v.x + e1.y * t1v.y + e1.z * t1v.z + e1.w * t1v.w;

        const float4* bp = (const float4*)(box + (size_t)row * DD + lane * 8);
        float4 x0 = bp[0], x1 = bp[1];
        // gather masked tag rows into one accumulator row -> ONE reduction
        float4 ya0 = {0.f,0.f,0.f,0.f}, ya1 = {0.f,0.f,0.f,0.f};
        float cnt = 0.0f;
        bool running = true;
        for (int k = 0; k < KK; k++) {
            int idx = bidx[row * KK + k];
            running = running && (idx != -1);
            int rel  = idx - LL;
            int relc = min(max(rel, 0), LL - 1);
            bool dg = get_mask(dtm_raw, b * (2 * LL) + LL + relc, mode);
            if (running && dg) {
                const float4* gp = (const float4*)(tag + ((size_t)b * LL + relc) * DD + lane * 8);
                float4 y0 = gp[0], y1 = gp[1];
                ya0.x += y0.x; ya0.y += y0.y; ya0.z += y0.z; ya0.w += y0.w;
                ya1.x += y1.x; ya1.y += y1.y; ya1.z += y1.z; ya1.w += y1.w;
                cnt += 1.0f;
            }
        }
        float dsum = x0.x * ya0.x + x0.y * ya0.y + x0.z * ya0.z + x0.w * ya0.w
                   + x1.x * ya1.x + x1.y * ya1.y + x1.z * ya1.z + x1.w * ya1.w;
        // two interleaved butterfly chains
        #pragma unroll
        for (int off = 32; off; off >>= 1) {
            dsum += __shfl_xor(dsum, off);
            de   += __shfl_xor(de,   off);
        }
        if (lane == 0) {
            ws[WS_PTRROW + row * 2 + 0] = dsum;
            ws[WS_PTRROW + row * 2 + 1] = cnt;
        }
        bool att = get_mask(att_raw, b * (2 * LL) + LL + i, mode);
        float bce = 0.0f, acnt = 0.0f;
        if (att) {
            bool dtm = get_mask(dtm_raw, b * (2 * LL) + LL + i, mode);
            float tgt = dtm ? 0.0f : 1.0f;
            float sp  = fmaxf(de, 0.0f) + log1pf(expf(-fabsf(de)));
            bce = sp - de * tgt;
            acnt = 1.0f;
        }
        if (lane == 0) { part[wv][0] = bce; part[wv][1] = acnt; }
        __syncthreads();
        if (tid == 0) {
            ws[WS_EMP + bid * 2 + 0] = part[0][0] + part[1][0] + part[2][0] + part[3][0];
            ws[WS_EMP + bid * 2 + 1] = part[0][1] + part[1][1] + part[2][1] + part[3][1];
        }
        return;
    }

    {
        // ---- cls: row softmax over V=64 ----
        int cb  = bid - 2048;
        int row = cb * 4 + wv;
        float x  = logits[(size_t)row * VV + lane];
        float mx = wave_red_max(x);
        float se = wave_red_sum(__expf(x - mx));
        float sx = wave_red_sum(x);
        float logZ = mx + logf(se);
        int t = tok[row];
        float xt = __shfl(x, t);
        float per = 0.9f * (logZ - xt) + 0.1f * (logZ - sx * (1.0f / VV));
        bool valid = (t > 3);
        if (lane == 0) {
            part[wv][0] = valid ? per : 0.0f;
            part[wv][1] = valid ? 1.0f : 0.0f;
        }
        __syncthreads();
        if (tid == 0) {
            ws[WS_CLS + cb * 2 + 0] = part[0][0] + part[1][0] + part[2][0] + part[3][0];
            ws[WS_CLS + cb * 2 + 1] = part[0][1] + part[1][1] + part[2][1] + part[3][1];
        }
    }
}

// ================= final combine: row log-coupling + tree reduce ============
__global__ __launch_bounds__(1024) void k_final(const float* __restrict__ ws, float* __restrict__ out) {
    __shared__ float red[16][12];
    int tid  = threadIdx.x;
    int lane = tid & 63, wv = tid >> 6;

    float q[12];
    #pragma unroll
    for (int i = 0; i < 12; i++) q[i] = 0.0f;

    // ptr: per-row cnt*log(den) - 10*sumd, 8 rows per thread
    #pragma unroll
    for (int i = 0; i < 8; i++) {
        int row = tid * 8 + i;
        const float* dp = ws + WS_DENP + (size_t)row * 8;
        float4 d0 = *(const float4*)dp;
        float4 d1 = *(const float4*)(dp + 4);
        float den = d0.x + d0.y + d0.z + d0.w + d1.x + d1.y + d1.z + d1.w;
        float sumd = ws[WS_PTRROW + row * 2 + 0];
        float cnt  = ws[WS_PTRROW + row * 2 + 1];
        q[2] += cnt * logf(den + EPSF) - INV_TEMP * sumd;
        q[3] += cnt;
    }
    #pragma unroll
    for (int it = 0; it < 2; it++) {
        int i = tid + it * 1024;
        q[0] += ws[WS_CLS + 2 * i];  q[1] += ws[WS_CLS + 2 * i + 1];
        q[8] += 0.0f;  // placeholder keeps unroll shape
    }
    // contr: 1024 pairs per matrix
    q[4] = ws[WS_CONTR + 2 * tid];
    q[5] = ws[WS_CONTR + 2 * tid + 1];
    q[6] = ws[WS_CONTR + 2 * (1024 + tid)];
    q[7] = ws[WS_CONTR + 2 * (1024 + tid) + 1];
    // empty: 2048 pairs; slot i has b = i>>8
    q[8]  = ws[WS_EMP + 2 * tid];
    q[9]  = ws[WS_EMP + 2 * tid + 1];
    q[10] = ws[WS_EMP + 2 * (tid + 1024)];
    q[11] = ws[WS_EMP + 2 * (tid + 1024) + 1];

    #pragma unroll
    for (int i = 0; i < 12; i++) {
        #pragma unroll
        for (int off = 32; off; off >>= 1) q[i] += __shfl_xor(q[i], off);
    }
    if (lane == 0) {
        #pragma unroll
        for (int i = 0; i < 12; i++) red[wv][i] = q[i];
    }
    __syncthreads();
    if (tid == 0) {
        float s[8];
        #pragma unroll
        for (int i = 0; i < 8; i++) s[i] = 0.0f;
        float es[8], ec[8];
        #pragma unroll
        for (int i = 0; i < 8; i++) { es[i] = 0.0f; ec[i] = 0.0f; }
        #pragma unroll
        for (int w = 0; w < 16; w++) {
            #pragma unroll
            for (int i = 0; i < 8; i++) s[i] += red[w][i];
            es[(w >> 2)]     += red[w][8];
            ec[(w >> 2)]     += red[w][9];
            es[(w >> 2) + 4] += red[w][10];
            ec[(w >> 2) + 4] += red[w][11];
        }
        float cls = s[0] / fmaxf(s[1], 1.0f);
        float ptr = (s[3] > 0.0f) ? s[2] / fmaxf(s[3], 1.0f) : 0.0f;
        float emp = 0.0f;
        #pragma unroll
        for (int b = 0; b < 8; b++) emp += es[b] / fmaxf(ec[b], 1.0f);
        emp *= (1.0f / BB);
        float rc = (s[5] > 0.0f) ? s[4] / fmaxf(s[5], 1.0f) : 0.0f;
        float cc = (s[7] > 0.0f) ? s[6] / fmaxf(s[7], 1.0f) : 0.0f;
        float tot = cls + ptr + emp + 0.5f * (rc + cc);
        out[0] = tot; out[1] = cls; out[2] = ptr;
        out[3] = emp; out[4] = rc;  out[5] = cc;
    }
}

extern "C" void kernel_launch(void* const* d_in, const int* in_sizes, int n_in,
                              void* d_out, int out_size, void* d_ws, size_t ws_size,
                              hipStream_t stream) {
    (void)in_sizes; (void)n_in; (void)out_size; (void)ws_size;
    const int*   token_ids = (const int*)  d_in[0];
    const int*   box_idx   = (const int*)  d_in[1];
    const void*  dtm       =               d_in[2];
    const void*  att       =               d_in[3];
    const float* tag_log   = (const float*)d_in[4];
    const float* box_proj  = (const float*)d_in[5];
    const float* tag_proj  = (const float*)d_in[6];
    const float* empty_p   = (const float*)d_in[7];
    const float* row_sim   = (const float*)d_in[8];
    const float* col_sim   = (const float*)d_in[9];
    const float* row_coef  = (const float*)d_in[10];
    const float* col_coef  = (const float*)d_in[11];
    float* ws  = (float*)d_ws;
    float* out = (float*)d_out;

    k_den  <<<BB * 64, 256, 0, stream>>>(box_proj, tag_proj, dtm, att, ws);
    k_contr<<<1024, 256, 0, stream>>>(row_sim, col_sim, row_coef, col_coef, ws);
    k_rest <<<4096, 256, 0, stream>>>(box_proj, tag_proj, tag_log, token_ids,
                                      box_idx, empty_p, dtm, att, ws);
    k_final<<<1, 1024, 0, stream>>>(ws, out);
}

// Round 10
// 77.802 us; speedup vs baseline: 1.2462x; 1.0903x over previous
//
#include <hip/hip_runtime.h>
#include <hip/hip_bf16.h>
#include <math.h>

#define BB 8
#define LL 1024
#define DD 512
#define VV 64
#define KK 8

constexpr float INV_TEMP = 10.0f;   // 1/TEMP
constexpr float EPSF     = 1e-10f;

// ---------------- workspace float layout (NO atomics, NO memset) ------------
#define WS_DENP   0                       // den partials [8192][8]
#define WS_CLS    (8192*8)                // cls  per-block {sum,cnt} x 2048
#define WS_EMP    (WS_CLS + 4096)        // emp  {sum,cnt} x 2048, slot = b*256+li
#define WS_CONTR  (WS_EMP + 4096)        // contr {sum,cnt} x 4096 (mat0:[0,2048), mat1:[2048,4096))
#define WS_PTRROW (WS_CONTR + 8192)      // ptr per-row {sumd,cnt} x 8192

typedef __attribute__((ext_vector_type(8))) short  short8;
typedef __attribute__((ext_vector_type(4))) float  f32x4;

// ---------------- bool-dtype detection ----------------
// MUST be fed attention_mask: its first L entries are all-True by construction.
__device__ __forceinline__ int mask_mode(const void* att_raw) {
    const unsigned* w = (const unsigned*)att_raw;
    unsigned w0 = w[0];
    if (w0 == 0x01010101u) return 0;           // bool/uint8
    if (w0 == 0x3f800000u) return 2;           // float32
    if (w0 == 1u) return (w[1] == 0u) ? 3 : 1; // int64 : int32
    return 0;
}
__device__ __forceinline__ bool get_mask(const void* p, int idx, int mode) {
    if (mode == 0) return ((const unsigned char*)p)[idx] != 0;
    if (mode == 1) return ((const int*)p)[idx] != 0;
    if (mode == 3) return ((const unsigned*)p)[2*idx] != 0u;
    return ((const float*)p)[idx] != 0.0f;
}

__device__ __forceinline__ float wave_red_sum(float v) {
    #pragma unroll
    for (int off = 32; off; off >>= 1) v += __shfl_xor(v, off);
    return v;
}
__device__ __forceinline__ float wave_red_max(float v) {
    #pragma unroll
    for (int off = 32; off; off >>= 1) v = fmaxf(v, __shfl_xor(v, off));
    return v;
}

__device__ __forceinline__ short bfb(float f) {
    __hip_bfloat16 h = __float2bfloat16(f);
    union { __hip_bfloat16 h; short u; } c; c.h = h; return c.u;
}

#define BM 128
#define BKD 32
#define ST 40            // LDS row stride in shorts (80 bytes)

// ================= den: bf16 MFMA GEMM + masked exp row-sum (unchanged) =====
// bid&7 = b -> all blocks of batch b land on XCD b; box[b]+tag[b] (4MB) stay L2-local.
__global__ __launch_bounds__(256) void k_den(const float* __restrict__ box,
                                             const float* __restrict__ tag,
                                             const void* __restrict__ dtm_raw,
                                             const void* __restrict__ att_raw,
                                             float* __restrict__ ws) {
    __shared__ short As[BM * ST];
    __shared__ short Bs[BM * ST];

    int bid   = blockIdx.x;
    int b     = bid & 7;
    int tile  = bid >> 3;
    int l0    = (tile >> 3) * BM;
    int ttile = tile & 7;
    int t0    = ttile * BM;

    int tid  = threadIdx.x;
    int lane = tid & 63;
    int wave = tid >> 6;
    int wr   = wave >> 1, wc = wave & 1;

    int srow  = tid >> 1;
    int shalf = tid & 1;
    const float* gA = box + ((size_t)b * LL + l0 + srow) * DD + shalf * 16;
    const float* gB = tag + ((size_t)b * LL + t0 + srow) * DD + shalf * 16;
    short* wA = &As[srow * ST + shalf * 16];
    short* wB = &Bs[srow * ST + shalf * 16];

    f32x4 acc[4][4];
    #pragma unroll
    for (int m = 0; m < 4; m++)
        #pragma unroll
        for (int n = 0; n < 4; n++) acc[m][n] = (f32x4){0.f, 0.f, 0.f, 0.f};

    int k0 = (lane >> 4) * 8;
    const short* rA = &As[(wr * 64 + (lane & 15)) * ST + k0];
    const short* rB = &Bs[(wc * 64 + (lane & 15)) * ST + k0];

    for (int d0 = 0; d0 < DD; d0 += BKD) {
        __syncthreads();
        float4 fa0 = *(const float4*)(gA + d0);
        float4 fa1 = *(const float4*)(gA + d0 + 4);
        float4 fa2 = *(const float4*)(gA + d0 + 8);
        float4 fa3 = *(const float4*)(gA + d0 + 12);
        float4 fb0 = *(const float4*)(gB + d0);
        float4 fb1 = *(const float4*)(gB + d0 + 4);
        float4 fb2 = *(const float4*)(gB + d0 + 8);
        float4 fb3 = *(const float4*)(gB + d0 + 12);
        short8 va0 = {bfb(fa0.x), bfb(fa0.y), bfb(fa0.z), bfb(fa0.w),
                      bfb(fa1.x), bfb(fa1.y), bfb(fa1.z), bfb(fa1.w)};
        short8 va1 = {bfb(fa2.x), bfb(fa2.y), bfb(fa2.z), bfb(fa2.w),
                      bfb(fa3.x), bfb(fa3.y), bfb(fa3.z), bfb(fa3.w)};
        short8 vb0 = {bfb(fb0.x), bfb(fb0.y), bfb(fb0.z), bfb(fb0.w),
                      bfb(fb1.x), bfb(fb1.y), bfb(fb1.z), bfb(fb1.w)};
        short8 vb1 = {bfb(fb2.x), bfb(fb2.y), bfb(fb2.z), bfb(fb2.w),
                      bfb(fb3.x), bfb(fb3.y), bfb(fb3.z), bfb(fb3.w)};
        *(short8*)wA       = va0;
        *(short8*)(wA + 8) = va1;
        *(short8*)wB       = vb0;
        *(short8*)(wB + 8) = vb1;
        __syncthreads();

        short8 af[4], bf[4];
        #pragma unroll
        for (int m = 0; m < 4; m++) af[m] = *(const short8*)(rA + m * 16 * ST);
        #pragma unroll
        for (int n = 0; n < 4; n++) bf[n] = *(const short8*)(rB + n * 16 * ST);
        #pragma unroll
        for (int m = 0; m < 4; m++)
            #pragma unroll
            for (int n = 0; n < 4; n++)
                acc[m][n] = __builtin_amdgcn_mfma_f32_16x16x32_bf16(af[m], bf[n], acc[m][n], 0, 0, 0);
    }

    int mode = mask_mode(att_raw);
    bool mk[4];
    #pragma unroll
    for (int n = 0; n < 4; n++) {
        int t = t0 + wc * 64 + n * 16 + (lane & 15);
        mk[n] = get_mask(dtm_raw, b * (2 * LL) + LL + t, mode);
    }
    #pragma unroll
    for (int m = 0; m < 4; m++) {
        #pragma unroll
        for (int reg = 0; reg < 4; reg++) {
            float s = 0.0f;
            #pragma unroll
            for (int n = 0; n < 4; n++)
                s += mk[n] ? __expf(acc[m][n][reg] * INV_TEMP) : 0.0f;
            #pragma unroll
            for (int off = 1; off < 16; off <<= 1) s += __shfl_xor(s, off);
            if ((lane & 15) == 0) {
                int l = l0 + wr * 64 + m * 16 + (lane >> 4) * 4 + reg;
                ws[WS_DENP + (b * LL + l) * 8 + ttile] = s;
            }
        }
    }
}

// ================= rest: ptr+empty [0,2048) | cls [2048,4096), XCD-pinned ====
// b = bid&7 matches k_den's mapping; launched right after k_den so box[b]/tag[b]
// rows and gathers hit XCD-b's L2 instead of crossing the fabric.
__global__ __launch_bounds__(256, 8) void k_rest(
        const float* __restrict__ box,     const float* __restrict__ tag,
        const float* __restrict__ logits,  const int* __restrict__ tok,
        const int* __restrict__ bidx,      const float* __restrict__ emptyp,
        const void* __restrict__ dtm_raw,  const void* __restrict__ att_raw,
        float* __restrict__ ws) {
    __shared__ float part[4][2];
    int bid  = blockIdx.x;
    int tid  = threadIdx.x;
    int lane = tid & 63;
    int wv   = tid >> 6;

    if (bid < 2048) {
        // ---- ptr + empty; block -> (b = bid&7, li = bid>>3), rows l = li*4+wv
        int b  = bid & 7;
        int li = bid >> 3;
        int i  = li * 4 + wv;
        int row = b * LL + i;
        int mode = mask_mode(att_raw);

        const float4* tp = (const float4*)(tag + (size_t)row * DD + lane * 8);
        const float4* ep = (const float4*)(emptyp + (size_t)b * DD + lane * 8);
        float4 t0v = tp[0], t1v = tp[1];
        float4 e0  = ep[0], e1  = ep[1];
        float de = e0.x * t0v.x + e0.y * t0v.y + e0.z * t0v.z + e0.w * t0v.w
                 + e1.x * t1v.x + e1.y * t1v.y + e1.z * t1v.z + e1.w * t1v.w;

        const float4* bp = (const float4*)(box + (size_t)row * DD + lane * 8);
        float4 x0 = bp[0], x1 = bp[1];
        // gather masked tag rows into one accumulator row -> ONE reduction
        float4 ya0 = {0.f,0.f,0.f,0.f}, ya1 = {0.f,0.f,0.f,0.f};
        float cnt = 0.0f;
        bool running = true;
        for (int k = 0; k < KK; k++) {
            int idx = bidx[row * KK + k];
            running = running && (idx != -1);
            int rel  = idx - LL;
            int relc = min(max(rel, 0), LL - 1);
            bool dg = get_mask(dtm_raw, b * (2 * LL) + LL + relc, mode);
            if (running && dg) {
                const float4* gp = (const float4*)(tag + ((size_t)b * LL + relc) * DD + lane * 8);
                float4 y0 = gp[0], y1 = gp[1];
                ya0.x += y0.x; ya0.y += y0.y; ya0.z += y0.z; ya0.w += y0.w;
                ya1.x += y1.x; ya1.y += y1.y; ya1.z += y1.z; ya1.w += y1.w;
                cnt += 1.0f;
            }
        }
        float dsum = x0.x * ya0.x + x0.y * ya0.y + x0.z * ya0.z + x0.w * ya0.w
                   + x1.x * ya1.x + x1.y * ya1.y + x1.z * ya1.z + x1.w * ya1.w;
        #pragma unroll
        for (int off = 32; off; off >>= 1) {
            dsum += __shfl_xor(dsum, off);
            de   += __shfl_xor(de,   off);
        }
        if (lane == 0) {
            ws[WS_PTRROW + row * 2 + 0] = dsum;
            ws[WS_PTRROW + row * 2 + 1] = cnt;
        }
        bool att = get_mask(att_raw, b * (2 * LL) + LL + i, mode);
        float bce = 0.0f, acnt = 0.0f;
        if (att) {
            bool dtm = get_mask(dtm_raw, b * (2 * LL) + LL + i, mode);
            float tgt = dtm ? 0.0f : 1.0f;
            float sp  = fmaxf(de, 0.0f) + log1pf(expf(-fabsf(de)));
            bce = sp - de * tgt;
            acnt = 1.0f;
        }
        if (lane == 0) { part[wv][0] = bce; part[wv][1] = acnt; }
        __syncthreads();
        if (tid == 0) {
            int slot = b * 256 + li;        // keep per-b grouping for k_final
            ws[WS_EMP + slot * 2 + 0] = part[0][0] + part[1][0] + part[2][0] + part[3][0];
            ws[WS_EMP + slot * 2 + 1] = part[0][1] + part[1][1] + part[2][1] + part[3][1];
        }
        return;
    }

    {
        // ---- cls: row softmax over V=64 (same b-pinned mapping, order-free sum)
        int cb = bid - 2048;
        int b  = cb & 7;
        int li = cb >> 3;
        int row = b * LL + li * 4 + wv;
        float x  = logits[(size_t)row * VV + lane];
        float mx = wave_red_max(x);
        float se = wave_red_sum(__expf(x - mx));
        float sx = wave_red_sum(x);
        float logZ = mx + logf(se);
        int t = tok[row];
        float xt = __shfl(x, t);
        float per = 0.9f * (logZ - xt) + 0.1f * (logZ - sx * (1.0f / VV));
        bool valid = (t > 3);
        if (lane == 0) {
            part[wv][0] = valid ? per : 0.0f;
            part[wv][1] = valid ? 1.0f : 0.0f;
        }
        __syncthreads();
        if (tid == 0) {
            ws[WS_CLS + cb * 2 + 0] = part[0][0] + part[1][0] + part[2][0] + part[3][0];
            ws[WS_CLS + cb * 2 + 1] = part[0][1] + part[1][1] + part[2][1] + part[3][1];
        }
    }
}

// ================= span contrastive (round-6 proven version, 45.4us) =========
// Shift-invariant form; no max pass (|s|<~57 -> no f32 overflow).
// Blocks 0..2047 are mat=0 rows, 2048..4095 mat=1 (4 rows/block).
__global__ void k_contr(const float* __restrict__ row_sim, const float* __restrict__ col_sim,
                        const float* __restrict__ row_coef, const float* __restrict__ col_coef,
                        float* __restrict__ ws) {
    __shared__ float part[4][2];
    int wv   = threadIdx.x >> 6;
    int gw   = blockIdx.x * 4 + wv;
    int lane = threadIdx.x & 63;
    int mat  = gw >> 13;           // 0: row, 1: col (uniform per block)
    int row  = gw & 8191;          // b*L + j
    int j    = row & 1023;
    const float* sim  = (mat ? col_sim  : row_sim)  + (size_t)row * LL;
    const float* coef = (mat ? col_coef : row_coef) + (size_t)row * LL;

    float4 v[4], c[4];
    #pragma unroll
    for (int e = 0; e < 4; e++) v[e] = ((const float4*)sim)[e * 64 + lane];
    #pragma unroll
    for (int e = 0; e < 4; e++) c[e] = ((const float4*)coef)[e * 64 + lane];

    float se = 0.0f, diag = 0.0f, sw = 0.0f, sws = 0.0f;
    #pragma unroll
    for (int e = 0; e < 4; e++) {
        float xs[4] = {v[e].x, v[e].y, v[e].z, v[e].w};
        float cs[4] = {c[e].x, c[e].y, c[e].z, c[e].w};
        #pragma unroll
        for (int q = 0; q < 4; q++) {
            float s  = xs[q] * INV_TEMP;
            float es = __expf(s);
            se += es;
            if (e * 256 + lane * 4 + q == j) diag = es;
            float w = cs[q] > 0.0f ? cs[q] : 0.0f;
            sw  += w;
            sws += w * s;
        }
    }
    #pragma unroll
    for (int off = 32; off; off >>= 1) {
        se   += __shfl_xor(se,   off);
        diag += __shfl_xor(diag, off);
        sw   += __shfl_xor(sw,   off);
        sws  += __shfl_xor(sws,  off);
    }
    float logden = logf(se - diag + EPSF);
    bool hp = sw > 0.0f;
    float loss = (logden * sw - sws) / (sw + EPSF);
    if (lane == 0) {
        part[wv][0] = hp ? loss : 0.0f;
        part[wv][1] = hp ? 1.0f : 0.0f;
    }
    __syncthreads();
    if (threadIdx.x == 0) {
        ws[WS_CONTR + blockIdx.x * 2 + 0] = part[0][0] + part[1][0] + part[2][0] + part[3][0];
        ws[WS_CONTR + blockIdx.x * 2 + 1] = part[0][1] + part[1][1] + part[2][1] + part[3][1];
    }
}

// ================= final combine: row log-coupling + tree reduce ============
// q: 0 cls_s,1 cls_c,2 ptr_s,3 ptr_c,4 row_s,5 row_c,6 col_s,7 col_c,
//    8 e0s,9 e0c,10 e1s,11 e1c
__global__ __launch_bounds__(1024) void k_final(const float* __restrict__ ws, float* __restrict__ out) {
    __shared__ float red[16][12];
    int tid  = threadIdx.x;
    int lane = tid & 63, wv = tid >> 6;

    float q[12];
    #pragma unroll
    for (int i = 0; i < 12; i++) q[i] = 0.0f;

    // ptr: per-row cnt*log(den) - 10*sumd, 8 rows per thread
    #pragma unroll
    for (int i = 0; i < 8; i++) {
        int row = tid * 8 + i;
        const float* dp = ws + WS_DENP + (size_t)row * 8;
        float4 d0 = *(const float4*)dp;
        float4 d1 = *(const float4*)(dp + 4);
        float den = d0.x + d0.y + d0.z + d0.w + d1.x + d1.y + d1.z + d1.w;
        float sumd = ws[WS_PTRROW + row * 2 + 0];
        float cnt  = ws[WS_PTRROW + row * 2 + 1];
        q[2] += cnt * logf(den + EPSF) - INV_TEMP * sumd;
        q[3] += cnt;
    }
    // cls: 2048 pairs
    #pragma unroll
    for (int it = 0; it < 2; it++) {
        int i = tid + it * 1024;
        q[0] += ws[WS_CLS + 2 * i];  q[1] += ws[WS_CLS + 2 * i + 1];
    }
    // contr: 4096 pairs; first 2048 row, last 2048 col
    q[4] = ws[WS_CONTR + 2 * tid]              + ws[WS_CONTR + 2 * (tid + 1024)];
    q[5] = ws[WS_CONTR + 2 * tid + 1]          + ws[WS_CONTR + 2 * (tid + 1024) + 1];
    q[6] = ws[WS_CONTR + 2 * (tid + 2048)]     + ws[WS_CONTR + 2 * (tid + 3072)];
    q[7] = ws[WS_CONTR + 2 * (tid + 2048) + 1] + ws[WS_CONTR + 2 * (tid + 3072) + 1];
    // empty: 2048 pairs; slot i has b = i>>8 (slot = b*256+li)
    q[8]  = ws[WS_EMP + 2 * tid];
    q[9]  = ws[WS_EMP + 2 * tid + 1];
    q[10] = ws[WS_EMP + 2 * (tid + 1024)];
    q[11] = ws[WS_EMP + 2 * (tid + 1024) + 1];

    #pragma unroll
    for (int i = 0; i < 12; i++) {
        #pragma unroll
        for (int off = 32; off; off >>= 1) q[i] += __shfl_xor(q[i], off);
    }
    if (lane == 0) {
        #pragma unroll
        for (int i = 0; i < 12; i++) red[wv][i] = q[i];
    }
    __syncthreads();
    if (tid == 0) {
        float s[8];
        #pragma unroll
        for (int i = 0; i < 8; i++) s[i] = 0.0f;
        float es[8], ec[8];
        #pragma unroll
        for (int i = 0; i < 8; i++) { es[i] = 0.0f; ec[i] = 0.0f; }
        #pragma unroll
        for (int w = 0; w < 16; w++) {
            #pragma unroll
            for (int i = 0; i < 8; i++) s[i] += red[w][i];
            es[(w >> 2)]     += red[w][8];
            ec[(w >> 2)]     += red[w][9];
            es[(w >> 2) + 4] += red[w][10];
            ec[(w >> 2) + 4] += red[w][11];
        }
        float cls = s[0] / fmaxf(s[1], 1.0f);
        float ptr = (s[3] > 0.0f) ? s[2] / fmaxf(s[3], 1.0f) : 0.0f;
        float emp = 0.0f;
        #pragma unroll
        for (int b = 0; b < 8; b++) emp += es[b] / fmaxf(ec[b], 1.0f);
        emp *= (1.0f / BB);
        float rc = (s[5] > 0.0f) ? s[4] / fmaxf(s[5], 1.0f) : 0.0f;
        float cc = (s[7] > 0.0f) ? s[6] / fmaxf(s[7], 1.0f) : 0.0f;
        float tot = cls + ptr + emp + 0.5f * (rc + cc);
        out[0] = tot; out[1] = cls; out[2] = ptr;
        out[3] = emp; out[4] = rc;  out[5] = cc;
    }
}

extern "C" void kernel_launch(void* const* d_in, const int* in_sizes, int n_in,
                              void* d_out, int out_size, void* d_ws, size_t ws_size,
                              hipStream_t stream) {
    (void)in_sizes; (void)n_in; (void)out_size; (void)ws_size;
    const int*   token_ids = (const int*)  d_in[0];
    const int*   box_idx   = (const int*)  d_in[1];
    const void*  dtm       =               d_in[2];
    const void*  att       =               d_in[3];
    const float* tag_log   = (const float*)d_in[4];
    const float* box_proj  = (const float*)d_in[5];
    const float* tag_proj  = (const float*)d_in[6];
    const float* empty_p   = (const float*)d_in[7];
    const float* row_sim   = (const float*)d_in[8];
    const float* col_sim   = (const float*)d_in[9];
    const float* row_coef  = (const float*)d_in[10];
    const float* col_coef  = (const float*)d_in[11];
    float* ws  = (float*)d_ws;
    float* out = (float*)d_out;

    // order: den warms each XCD's L2 with box[b]+tag[b]; rest consumes it
    // L2-hot; contr's 128MB stream (which evicts L2) runs last.
    k_den  <<<BB * 64, 256, 0, stream>>>(box_proj, tag_proj, dtm, att, ws);
    k_rest <<<4096, 256, 0, stream>>>(box_proj, tag_proj, tag_log, token_ids,
                                      box_idx, empty_p, dtm, att, ws);
    k_contr<<<4096, 256, 0, stream>>>(row_sim, col_sim, row_coef, col_coef, ws);
    k_final<<<1, 1024, 0, stream>>>(ws, out);
}

// Round 11
// 75.772 us; speedup vs baseline: 1.2796x; 1.0268x over previous
//
#include <hip/hip_runtime.h>
#include <hip/hip_bf16.h>
#include <math.h>

#define BB 8
#define LL 1024
#define DD 512
#define VV 64
#define KK 8

constexpr float INV_TEMP = 10.0f;   // 1/TEMP
constexpr float EPSF     = 1e-10f;

// ---------------- workspace float layout (NO atomics, NO memset) ------------
#define WS_DENP   0                       // den partials [8192][8]
#define WS_CLS    (8192*8)                // cls  per-block {sum,cnt} x 2048
#define WS_EMP    (WS_CLS + 4096)        // emp  {sum,cnt} x 2048, slot = b*256+li
#define WS_CONTR  (WS_EMP + 4096)        // contr {sum,cnt} x 4096 (mat0:[0,2048), mat1:[2048,4096))
#define WS_PTRROW (WS_CONTR + 8192)      // ptr per-row {sumd,cnt} x 8192

typedef __attribute__((ext_vector_type(8))) short  short8;
typedef __attribute__((ext_vector_type(4))) float  f32x4;

// ---------------- bool-dtype detection ----------------
// MUST be fed attention_mask: its first L entries are all-True by construction.
__device__ __forceinline__ int mask_mode(const void* att_raw) {
    const unsigned* w = (const unsigned*)att_raw;
    unsigned w0 = w[0];
    if (w0 == 0x01010101u) return 0;           // bool/uint8
    if (w0 == 0x3f800000u) return 2;           // float32
    if (w0 == 1u) return (w[1] == 0u) ? 3 : 1; // int64 : int32
    return 0;
}
__device__ __forceinline__ bool get_mask(const void* p, int idx, int mode) {
    if (mode == 0) return ((const unsigned char*)p)[idx] != 0;
    if (mode == 1) return ((const int*)p)[idx] != 0;
    if (mode == 3) return ((const unsigned*)p)[2*idx] != 0u;
    return ((const float*)p)[idx] != 0.0f;
}

__device__ __forceinline__ float wave_red_sum(float v) {
    #pragma unroll
    for (int off = 32; off; off >>= 1) v += __shfl_xor(v, off);
    return v;
}
__device__ __forceinline__ float wave_red_max(float v) {
    #pragma unroll
    for (int off = 32; off; off >>= 1) v = fmaxf(v, __shfl_xor(v, off));
    return v;
}

__device__ __forceinline__ short bfb(float f) {
    __hip_bfloat16 h = __float2bfloat16(f);
    union { __hip_bfloat16 h; short u; } c; c.h = h; return c.u;
}

#define BM 128
#define BKD 32
#define ST 40            // LDS row stride in shorts (80 bytes)

// ================= den: bf16 MFMA GEMM + masked exp row-sum (unchanged) =====
// bid&7 = b -> all blocks of batch b land on XCD b; box[b]+tag[b] (4MB) stay L2-local.
__global__ __launch_bounds__(256) void k_den(const float* __restrict__ box,
                                             const float* __restrict__ tag,
                                             const void* __restrict__ dtm_raw,
                                             const void* __restrict__ att_raw,
                                             float* __restrict__ ws) {
    __shared__ short As[BM * ST];
    __shared__ short Bs[BM * ST];

    int bid   = blockIdx.x;
    int b     = bid & 7;
    int tile  = bid >> 3;
    int l0    = (tile >> 3) * BM;
    int ttile = tile & 7;
    int t0    = ttile * BM;

    int tid  = threadIdx.x;
    int lane = tid & 63;
    int wave = tid >> 6;
    int wr   = wave >> 1, wc = wave & 1;

    int srow  = tid >> 1;
    int shalf = tid & 1;
    const float* gA = box + ((size_t)b * LL + l0 + srow) * DD + shalf * 16;
    const float* gB = tag + ((size_t)b * LL + t0 + srow) * DD + shalf * 16;
    short* wA = &As[srow * ST + shalf * 16];
    short* wB = &Bs[srow * ST + shalf * 16];

    f32x4 acc[4][4];
    #pragma unroll
    for (int m = 0; m < 4; m++)
        #pragma unroll
        for (int n = 0; n < 4; n++) acc[m][n] = (f32x4){0.f, 0.f, 0.f, 0.f};

    int k0 = (lane >> 4) * 8;
    const short* rA = &As[(wr * 64 + (lane & 15)) * ST + k0];
    const short* rB = &Bs[(wc * 64 + (lane & 15)) * ST + k0];

    for (int d0 = 0; d0 < DD; d0 += BKD) {
        __syncthreads();
        float4 fa0 = *(const float4*)(gA + d0);
        float4 fa1 = *(const float4*)(gA + d0 + 4);
        float4 fa2 = *(const float4*)(gA + d0 + 8);
        float4 fa3 = *(const float4*)(gA + d0 + 12);
        float4 fb0 = *(const float4*)(gB + d0);
        float4 fb1 = *(const float4*)(gB + d0 + 4);
        float4 fb2 = *(const float4*)(gB + d0 + 8);
        float4 fb3 = *(const float4*)(gB + d0 + 12);
        short8 va0 = {bfb(fa0.x), bfb(fa0.y), bfb(fa0.z), bfb(fa0.w),
                      bfb(fa1.x), bfb(fa1.y), bfb(fa1.z), bfb(fa1.w)};
        short8 va1 = {bfb(fa2.x), bfb(fa2.y), bfb(fa2.z), bfb(fa2.w),
                      bfb(fa3.x), bfb(fa3.y), bfb(fa3.z), bfb(fa3.w)};
        short8 vb0 = {bfb(fb0.x), bfb(fb0.y), bfb(fb0.z), bfb(fb0.w),
                      bfb(fb1.x), bfb(fb1.y), bfb(fb1.z), bfb(fb1.w)};
        short8 vb1 = {bfb(fb2.x), bfb(fb2.y), bfb(fb2.z), bfb(fb2.w),
                      bfb(fb3.x), bfb(fb3.y), bfb(fb3.z), bfb(fb3.w)};
        *(short8*)wA       = va0;
        *(short8*)(wA + 8) = va1;
        *(short8*)wB       = vb0;
        *(short8*)(wB + 8) = vb1;
        __syncthreads();

        short8 af[4], bf[4];
        #pragma unroll
        for (int m = 0; m < 4; m++) af[m] = *(const short8*)(rA + m * 16 * ST);
        #pragma unroll
        for (int n = 0; n < 4; n++) bf[n] = *(const short8*)(rB + n * 16 * ST);
        #pragma unroll
        for (int m = 0; m < 4; m++)
            #pragma unroll
            for (int n = 0; n < 4; n++)
                acc[m][n] = __builtin_amdgcn_mfma_f32_16x16x32_bf16(af[m], bf[n], acc[m][n], 0, 0, 0);
    }

    int mode = mask_mode(att_raw);
    bool mk[4];
    #pragma unroll
    for (int n = 0; n < 4; n++) {
        int t = t0 + wc * 64 + n * 16 + (lane & 15);
        mk[n] = get_mask(dtm_raw, b * (2 * LL) + LL + t, mode);
    }
    #pragma unroll
    for (int m = 0; m < 4; m++) {
        #pragma unroll
        for (int reg = 0; reg < 4; reg++) {
            float s = 0.0f;
            #pragma unroll
            for (int n = 0; n < 4; n++)
                s += mk[n] ? __expf(acc[m][n][reg] * INV_TEMP) : 0.0f;
            #pragma unroll
            for (int off = 1; off < 16; off <<= 1) s += __shfl_xor(s, off);
            if ((lane & 15) == 0) {
                int l = l0 + wr * 64 + m * 16 + (lane >> 4) * 4 + reg;
                ws[WS_DENP + (b * LL + l) * 8 + ttile] = s;
            }
        }
    }
}

// ====== light2: ptr+empty [0,2048) | cls [2048,4096) | contr [4096,8192) =====
// rest blocks first (L2-hot right after k_den, XCD-pinned via bid&7; range base
// multiple of 8 preserves round-robin XCD affinity). contr blocks dominate the
// tail and saturate the fabric while rest/cls ride the idle L2/VALU slots.
__global__ __launch_bounds__(256, 8) void k_light2(
        const float* __restrict__ box,     const float* __restrict__ tag,
        const float* __restrict__ logits,  const int* __restrict__ tok,
        const int* __restrict__ bidx,      const float* __restrict__ emptyp,
        const float* __restrict__ row_sim, const float* __restrict__ col_sim,
        const float* __restrict__ row_coef,const float* __restrict__ col_coef,
        const void* __restrict__ dtm_raw,  const void* __restrict__ att_raw,
        float* __restrict__ ws) {
    __shared__ float part[4][2];
    int bid  = blockIdx.x;
    int tid  = threadIdx.x;
    int lane = tid & 63;
    int wv   = tid >> 6;

    if (bid < 2048) {
        // ---- ptr + empty; block -> (b = bid&7, li = bid>>3), rows i = li*4+wv
        int b  = bid & 7;
        int li = bid >> 3;
        int i  = li * 4 + wv;
        int row = b * LL + i;
        int mode = mask_mode(att_raw);

        const float4* tp = (const float4*)(tag + (size_t)row * DD + lane * 8);
        const float4* ep = (const float4*)(emptyp + (size_t)b * DD + lane * 8);
        float4 t0v = tp[0], t1v = tp[1];
        float4 e0  = ep[0], e1  = ep[1];
        float de = e0.x * t0v.x + e0.y * t0v.y + e0.z * t0v.z + e0.w * t0v.w
                 + e1.x * t1v.x + e1.y * t1v.y + e1.z * t1v.z + e1.w * t1v.w;

        const float4* bp = (const float4*)(box + (size_t)row * DD + lane * 8);
        float4 x0 = bp[0], x1 = bp[1];
        // gather masked tag rows into one accumulator row -> ONE reduction
        float4 ya0 = {0.f,0.f,0.f,0.f}, ya1 = {0.f,0.f,0.f,0.f};
        float cnt = 0.0f;
        bool running = true;
        for (int k = 0; k < KK; k++) {
            int idx = bidx[row * KK + k];
            running = running && (idx != -1);
            int rel  = idx - LL;
            int relc = min(max(rel, 0), LL - 1);
            bool dg = get_mask(dtm_raw, b * (2 * LL) + LL + relc, mode);
            if (running && dg) {
                const float4* gp = (const float4*)(tag + ((size_t)b * LL + relc) * DD + lane * 8);
                float4 y0 = gp[0], y1 = gp[1];
                ya0.x += y0.x; ya0.y += y0.y; ya0.z += y0.z; ya0.w += y0.w;
                ya1.x += y1.x; ya1.y += y1.y; ya1.z += y1.z; ya1.w += y1.w;
                cnt += 1.0f;
            }
        }
        float dsum = x0.x * ya0.x + x0.y * ya0.y + x0.z * ya0.z + x0.w * ya0.w
                   + x1.x * ya1.x + x1.y * ya1.y + x1.z * ya1.z + x1.w * ya1.w;
        #pragma unroll
        for (int off = 32; off; off >>= 1) {
            dsum += __shfl_xor(dsum, off);
            de   += __shfl_xor(de,   off);
        }
        if (lane == 0) {
            ws[WS_PTRROW + row * 2 + 0] = dsum;
            ws[WS_PTRROW + row * 2 + 1] = cnt;
        }
        bool att = get_mask(att_raw, b * (2 * LL) + LL + i, mode);
        float bce = 0.0f, acnt = 0.0f;
        if (att) {
            bool dtm = get_mask(dtm_raw, b * (2 * LL) + LL + i, mode);
            float tgt = dtm ? 0.0f : 1.0f;
            float sp  = fmaxf(de, 0.0f) + log1pf(expf(-fabsf(de)));
            bce = sp - de * tgt;
            acnt = 1.0f;
        }
        if (lane == 0) { part[wv][0] = bce; part[wv][1] = acnt; }
        __syncthreads();
        if (tid == 0) {
            int slot = b * 256 + li;        // keep per-b grouping for k_final
            ws[WS_EMP + slot * 2 + 0] = part[0][0] + part[1][0] + part[2][0] + part[3][0];
            ws[WS_EMP + slot * 2 + 1] = part[0][1] + part[1][1] + part[2][1] + part[3][1];
        }
        return;
    }

    if (bid < 4096) {
        // ---- cls: row softmax over V=64 (order-free sum) ----
        int cb = bid - 2048;
        int b  = cb & 7;
        int li = cb >> 3;
        int row = b * LL + li * 4 + wv;
        float x  = logits[(size_t)row * VV + lane];
        float mx = wave_red_max(x);
        float se = wave_red_sum(__expf(x - mx));
        float sx = wave_red_sum(x);
        float logZ = mx + logf(se);
        int t = tok[row];
        float xt = __shfl(x, t);
        float per = 0.9f * (logZ - xt) + 0.1f * (logZ - sx * (1.0f / VV));
        bool valid = (t > 3);
        if (lane == 0) {
            part[wv][0] = valid ? per : 0.0f;
            part[wv][1] = valid ? 1.0f : 0.0f;
        }
        __syncthreads();
        if (tid == 0) {
            ws[WS_CLS + cb * 2 + 0] = part[0][0] + part[1][0] + part[2][0] + part[3][0];
            ws[WS_CLS + cb * 2 + 1] = part[0][1] + part[1][1] + part[2][1] + part[3][1];
        }
        return;
    }

    {
        // ---- span contrastive (shift-invariant single pass) ----
        int cb   = bid - 4096;            // 0..4095
        int gw   = cb * 4 + wv;
        int mat  = gw >> 13;              // 0: row, 1: col
        int row  = gw & 8191;             // b*L + j
        int j    = row & 1023;
        const float* sim  = (mat ? col_sim  : row_sim)  + (size_t)row * LL;
        const float* coef = (mat ? col_coef : row_coef) + (size_t)row * LL;

        float4 v[4], c[4];
        #pragma unroll
        for (int e = 0; e < 4; e++) v[e] = ((const float4*)sim)[e * 64 + lane];
        #pragma unroll
        for (int e = 0; e < 4; e++) c[e] = ((const float4*)coef)[e * 64 + lane];

        float se = 0.0f, diag = 0.0f, sw = 0.0f, sws = 0.0f;
        #pragma unroll
        for (int e = 0; e < 4; e++) {
            float xs[4] = {v[e].x, v[e].y, v[e].z, v[e].w};
            float cs[4] = {c[e].x, c[e].y, c[e].z, c[e].w};
            #pragma unroll
            for (int q = 0; q < 4; q++) {
                float s  = xs[q] * INV_TEMP;
                float es = __expf(s);
                se += es;
                if (e * 256 + lane * 4 + q == j) diag = es;
                float w = cs[q] > 0.0f ? cs[q] : 0.0f;
                sw  += w;
                sws += w * s;
            }
        }
        #pragma unroll
        for (int off = 32; off; off >>= 1) {
            se   += __shfl_xor(se,   off);
            diag += __shfl_xor(diag, off);
            sw   += __shfl_xor(sw,   off);
            sws  += __shfl_xor(sws,  off);
        }
        float logden = logf(se - diag + EPSF);
        bool hp = sw > 0.0f;
        float loss = (logden * sw - sws) / (sw + EPSF);
        if (lane == 0) {
            part[wv][0] = hp ? loss : 0.0f;
            part[wv][1] = hp ? 1.0f : 0.0f;
        }
        __syncthreads();
        if (tid == 0) {
            ws[WS_CONTR + cb * 2 + 0] = part[0][0] + part[1][0] + part[2][0] + part[3][0];
            ws[WS_CONTR + cb * 2 + 1] = part[0][1] + part[1][1] + part[2][1] + part[3][1];
        }
    }
}

// ================= final combine: row log-coupling + tree reduce ============
// q: 0 cls_s,1 cls_c,2 ptr_s,3 ptr_c,4 row_s,5 row_c,6 col_s,7 col_c,
//    8 e0s,9 e0c,10 e1s,11 e1c
__global__ __launch_bounds__(1024) void k_final(const float* __restrict__ ws, float* __restrict__ out) {
    __shared__ float red[16][12];
    int tid  = threadIdx.x;
    int lane = tid & 63, wv = tid >> 6;

    float q[12];
    #pragma unroll
    for (int i = 0; i < 12; i++) q[i] = 0.0f;

    // ptr: per-row cnt*log(den) - 10*sumd, 8 rows per thread
    #pragma unroll
    for (int i = 0; i < 8; i++) {
        int row = tid * 8 + i;
        const float* dp = ws + WS_DENP + (size_t)row * 8;
        float4 d0 = *(const float4*)dp;
        float4 d1 = *(const float4*)(dp + 4);
        float den = d0.x + d0.y + d0.z + d0.w + d1.x + d1.y + d1.z + d1.w;
        float sumd = ws[WS_PTRROW + row * 2 + 0];
        float cnt  = ws[WS_PTRROW + row * 2 + 1];
        q[2] += cnt * logf(den + EPSF) - INV_TEMP * sumd;
        q[3] += cnt;
    }
    // cls: 2048 pairs
    #pragma unroll
    for (int it = 0; it < 2; it++) {
        int i = tid + it * 1024;
        q[0] += ws[WS_CLS + 2 * i];  q[1] += ws[WS_CLS + 2 * i + 1];
    }
    // contr: 4096 pairs; first 2048 row, last 2048 col
    q[4] = ws[WS_CONTR + 2 * tid]              + ws[WS_CONTR + 2 * (tid + 1024)];
    q[5] = ws[WS_CONTR + 2 * tid + 1]          + ws[WS_CONTR + 2 * (tid + 1024) + 1];
    q[6] = ws[WS_CONTR + 2 * (tid + 2048)]     + ws[WS_CONTR + 2 * (tid + 3072)];
    q[7] = ws[WS_CONTR + 2 * (tid + 2048) + 1] + ws[WS_CONTR + 2 * (tid + 3072) + 1];
    // empty: 2048 pairs; slot i has b = i>>8 (slot = b*256+li)
    q[8]  = ws[WS_EMP + 2 * tid];
    q[9]  = ws[WS_EMP + 2 * tid + 1];
    q[10] = ws[WS_EMP + 2 * (tid + 1024)];
    q[11] = ws[WS_EMP + 2 * (tid + 1024) + 1];

    #pragma unroll
    for (int i = 0; i < 12; i++) {
        #pragma unroll
        for (int off = 32; off; off >>= 1) q[i] += __shfl_xor(q[i], off);
    }
    if (lane == 0) {
        #pragma unroll
        for (int i = 0; i < 12; i++) red[wv][i] = q[i];
    }
    __syncthreads();
    if (tid == 0) {
        float s[8];
        #pragma unroll
        for (int i = 0; i < 8; i++) s[i] = 0.0f;
        float es[8], ec[8];
        #pragma unroll
        for (int i = 0; i < 8; i++) { es[i] = 0.0f; ec[i] = 0.0f; }
        #pragma unroll
        for (int w = 0; w < 16; w++) {
            #pragma unroll
            for (int i = 0; i < 8; i++) s[i] += red[w][i];
            es[(w >> 2)]     += red[w][8];
            ec[(w >> 2)]     += red[w][9];
            es[(w >> 2) + 4] += red[w][10];
            ec[(w >> 2) + 4] += red[w][11];
        }
        float cls = s[0] / fmaxf(s[1], 1.0f);
        float ptr = (s[3] > 0.0f) ? s[2] / fmaxf(s[3], 1.0f) : 0.0f;
        float emp = 0.0f;
        #pragma unroll
        for (int b = 0; b < 8; b++) emp += es[b] / fmaxf(ec[b], 1.0f);
        emp *= (1.0f / BB);
        float rc = (s[5] > 0.0f) ? s[4] / fmaxf(s[5], 1.0f) : 0.0f;
        float cc = (s[7] > 0.0f) ? s[6] / fmaxf(s[7], 1.0f) : 0.0f;
        float tot = cls + ptr + emp + 0.5f * (rc + cc);
        out[0] = tot; out[1] = cls; out[2] = ptr;
        out[3] = emp; out[4] = rc;  out[5] = cc;
    }
}

extern "C" void kernel_launch(void* const* d_in, const int* in_sizes, int n_in,
                              void* d_out, int out_size, void* d_ws, size_t ws_size,
                              hipStream_t stream) {
    (void)in_sizes; (void)n_in; (void)out_size; (void)ws_size;
    const int*   token_ids = (const int*)  d_in[0];
    const int*   box_idx   = (const int*)  d_in[1];
    const void*  dtm       =               d_in[2];
    const void*  att       =               d_in[3];
    const float* tag_log   = (const float*)d_in[4];
    const float* box_proj  = (const float*)d_in[5];
    const float* tag_proj  = (const float*)d_in[6];
    const float* empty_p   = (const float*)d_in[7];
    const float* row_sim   = (const float*)d_in[8];
    const float* col_sim   = (const float*)d_in[9];
    const float* row_coef  = (const float*)d_in[10];
    const float* col_coef  = (const float*)d_in[11];
    float* ws  = (float*)d_ws;
    float* out = (float*)d_out;

    // den warms each XCD's L2 with box[b]+tag[b]; light2 runs rest/cls L2-hot
    // overlapped with contr's fabric-bound stream; final combines.
    k_den   <<<BB * 64, 256, 0, stream>>>(box_proj, tag_proj, dtm, att, ws);
    k_light2<<<8192, 256, 0, stream>>>(box_proj, tag_proj, tag_log, token_ids,
                                       box_idx, empty_p, row_sim, col_sim,
                                       row_coef, col_coef, dtm, att, ws);
    k_final <<<1, 1024, 0, stream>>>(ws, out);
}